// Round 3
// baseline (4842.273 us; speedup 1.0000x reference)
//
#include <hip/hip_runtime.h>

#define B 128
#define N 64
#define D 20
#define H 256
#define WMH 1024
#define CAUG 21
#define SIG 231
#define C 232
#define CP 240          // padded C
#define KA 288          // augmented K (256 + bias row + pad)
#define NSEG 63
#define NPH 126
#define HSTEP (1.0f/63.0f)
#define EPS 1e-5f

typedef __attribute__((ext_vector_type(8))) short short8;
typedef __attribute__((ext_vector_type(4))) float f32x4;
typedef __attribute__((ext_vector_type(4))) unsigned int uint4v;
typedef unsigned int uint;

__device__ inline short f2bf(float f) {
  uint u = __float_as_uint(f);
  uint r = (u + 0x7fffu + ((u >> 16) & 1u)) >> 16;
  return (short)r;
}
__device__ inline float bf2f(short h) {
  return __uint_as_float(((uint)(unsigned short)h) << 16);
}
#define MFMA16(a, b, c) __builtin_amdgcn_mfma_f32_16x16x32_bf16((a), (b), (c), 0, 0, 0)

// --- relaxed agent-scope scalar coherent ops (compiler-emitted, write-through)
__device__ inline void cstoreu(uint* p, uint v) {
  __hip_atomic_store(p, v, __ATOMIC_RELAXED, __HIP_MEMORY_SCOPE_AGENT);
}
__device__ inline void cstoref(float* p, float v) {
  __hip_atomic_store(p, v, __ATOMIC_RELAXED, __HIP_MEMORY_SCOPE_AGENT);
}
__device__ inline int cloadi(const int* p) {
  return __hip_atomic_load(p, __ATOMIC_RELAXED, __HIP_MEMORY_SCOPE_AGENT);
}
__device__ inline void cstorei(int* p, int v) {
  __hip_atomic_store(p, v, __ATOMIC_RELAXED, __HIP_MEMORY_SCOPE_AGENT);
}

// single-line flag wait; ONE polling thread per block. On success, wave 0
// issues an AGENT-scope acquire fence: emits buffer_inv (L1+L2 invalidate),
// which makes subsequent PLAIN cached loads coherent with other XCDs'
// write-through stores. All other waves are ordered by the barrier.
__device__ inline void waitflag(const int* f, int v) {
  if (threadIdx.x < 64) {
    if (threadIdx.x == 0) {
      while (cloadi(f) < v) __builtin_amdgcn_s_sleep(2);
    }
    __builtin_amdgcn_fence(__ATOMIC_ACQUIRE, "agent");
  }
  __syncthreads();
}
// producers: returning fetch_add on counter line; last one publishes flag.
// Producer data stores are sc0sc1 write-through (MALL-visible at vmcnt=0).
__device__ inline void siggroup(int* c, int nprod, int* flag) {
  __builtin_amdgcn_fence(__ATOMIC_RELEASE, "workgroup");   // vmcnt drain only
  __syncthreads();
  if (threadIdx.x == 0) {
    int old = __hip_atomic_fetch_add(c, 1, __ATOMIC_RELAXED, __HIP_MEMORY_SCOPE_AGENT);
    if (old == nprod - 1) cstorei(flag, 1);
  }
}

__device__ inline void unpk(uint4v a, uint4v b, short8& ah, short8& al) {
#pragma unroll
  for (int e = 0; e < 4; e++) {
    ah[e]     = (short)(a[e] >> 16); al[e]     = (short)(a[e] & 0xffffu);
    ah[4 + e] = (short)(b[e] >> 16); al[4 + e] = (short)(b[e] & 0xffffu);
  }
}

// ---------------------------------------------------------------------------
// Kernel 1: depth-2 log-signature + LayerNorm -> y (B,N,C)
// ---------------------------------------------------------------------------
__global__ __launch_bounds__(256) void k_logsig(const float* __restrict__ x,
                                                const float* __restrict__ sg,
                                                const float* __restrict__ sb,
                                                float* __restrict__ y) {
  __shared__ float yb[N][C];
  int b = blockIdx.x, tid = threadIdx.x;
  for (int ii = tid; ii < N * CAUG; ii += 256) {
    int n = ii / CAUG, j = ii % CAUG;
    float v = (j == 0) ? (n * (1.0f / 63.0f)) : x[(b * N + n) * D + (j - 1)];
    yb[n][1 + j] = v;
  }
  __syncthreads();
  if (tid < 210) {
    int i = 0, rem = tid;
    while (rem >= (CAUG - 1) - i) { rem -= (CAUG - 1) - i; i++; }
    int j = i + 1 + rem;
    float acc = 0.f, pi_prev = 0.f, pj_prev = 0.f;
    for (int n = 0; n < N; n++) {
      float pi = yb[n][1 + i], pj = yb[n][1 + j];
      float di = pi - pi_prev, dj = pj - pj_prev;
      acc += 0.5f * (pi_prev * dj - di * pj_prev);
      yb[n][1 + CAUG + tid] = acc;
      pi_prev = pi; pj_prev = pj;
    }
  }
  __syncthreads();
  int w = tid >> 6, l = tid & 63;
  for (int n = w; n < N; n += 4) {
    float s1 = 0.f, s2 = 0.f;
    for (int s = l; s < SIG; s += 64) { float v = yb[n][1 + s]; s1 += v; s2 += v * v; }
    for (int off = 32; off > 0; off >>= 1) { s1 += __shfl_down(s1, off); s2 += __shfl_down(s2, off); }
    s1 = __shfl(s1, 0); s2 = __shfl(s2, 0);
    float mean = s1 * (1.0f / SIG);
    float var  = s2 * (1.0f / SIG) - mean * mean;
    float rs = rsqrtf(var + EPS);
    float* yrow = y + ((size_t)b * N + n) * C;
    if (l == 0) yrow[0] = n * (1.0f / 63.0f);
    for (int s = l; s < SIG; s += 64)
      yrow[1 + s] = (yb[n][1 + s] - mean) * rs * sg[s] + sb[s];
  }
}

// ---------------------------------------------------------------------------
// Kernel 2: natural cubic spline -> d_knot, d_mid (NSEG, B, CP) zero-padded
// ---------------------------------------------------------------------------
__global__ __launch_bounds__(256) void k_spline(const float* __restrict__ y,
                                                float* __restrict__ dknot,
                                                float* __restrict__ dmid) {
  __shared__ float yb[N * C];
  __shared__ float cp_s[62], id_s[62];
  int b = blockIdx.x, tid = threadIdx.x;
  for (int ii = tid; ii < N * C; ii += 256) yb[ii] = y[(size_t)b * N * C + ii];
  if (tid == 0) {
    const float a = HSTEP / 6.f, bb = 2.f * HSTEP / 3.f;
    float id0 = 1.f / bb; id_s[0] = id0; cp_s[0] = a * id0;
    for (int j = 1; j < 62; j++) {
      float den = bb - a * cp_s[j - 1];
      float idj = 1.f / den; id_s[j] = idj; cp_s[j] = a * idj;
    }
  }
  __syncthreads();
  int c = tid;
  if (c >= 232 && c < CP) {
    for (int n = 0; n < NSEG; n++) {
      dknot[((size_t)n * B + b) * CP + c] = 0.f;
      dmid [((size_t)n * B + b) * CP + c] = 0.f;
    }
  } else if (c < 232) {
    const float a = HSTEP / 6.f;
    float dp[62];
    dp[0] = (yb[2 * C + c] - 2.f * yb[1 * C + c] + yb[0 * C + c]) * 63.0f * id_s[0];
#pragma unroll
    for (int j = 1; j < 62; j++) {
      float rj = (yb[(j + 2) * C + c] - 2.f * yb[(j + 1) * C + c] + yb[j * C + c]) * 63.0f;
      dp[j] = (rj - a * dp[j - 1]) * id_s[j];
    }
#pragma unroll
    for (int j = 60; j >= 0; j--) dp[j] -= cp_s[j] * dp[j + 1];
#pragma unroll
    for (int n = 0; n < NSEG; n++) {
      float Mn  = (n == 0)  ? 0.f : dp[n - 1];
      float Mn1 = (n == 62) ? 0.f : dp[n];
      float dy = (yb[(n + 1) * C + c] - yb[n * C + c]) * 63.0f;
      dknot[((size_t)n * B + b) * CP + c] = dy - (HSTEP / 6.f)  * (2.f * Mn + Mn1);
      dmid [((size_t)n * B + b) * CP + c] = dy + (HSTEP / 24.f) * (Mn - Mn1);
    }
  }
}

// ---------------------------------------------------------------------------
// Kernel 3: initial hidden state -> z (f32) and Xu (packed hi|lo bf16)
// ---------------------------------------------------------------------------
__global__ __launch_bounds__(256) void k_h0(const float* __restrict__ x,
                                            const float* __restrict__ hW1,
                                            const float* __restrict__ hb1,
                                            const float* __restrict__ hW2,
                                            const float* __restrict__ hb2,
                                            float* __restrict__ z,
                                            uint* __restrict__ Xu) {
  __shared__ float r[H];
  int b = blockIdx.x, tid = threadIdx.x;
  float s = hb1[tid];
#pragma unroll
  for (int d = 0; d < D; d++) s += x[(size_t)(b * N) * D + d] * hW1[d * H + tid];
  r[tid] = fmaxf(s, 0.f);
  __syncthreads();
  float s2 = hb2[tid];
  for (int k = 0; k < H; k++) s2 += r[k] * hW2[k * H + tid];
  z[b * H + tid] = s2;
  short hi = f2bf(s2);
  short lo = f2bf(s2 - bf2f(hi));
  Xu[b * H + tid] = ((uint)(unsigned short)hi << 16) | (unsigned short)lo;
}

// ---------------------------------------------------------------------------
// Prep: transpose fW4 (256 x 59392) f32 -> W4T [h*240+c][288] bf16
// ---------------------------------------------------------------------------
__global__ __launch_bounds__(256) void k_prep_t(const float* __restrict__ fW4,
                                                short* __restrict__ W4T) {
  __shared__ float tile[64][65];
  int m0 = blockIdx.x * 64, k0 = blockIdx.y * 64;
  int lane = threadIdx.x & 63, wr = threadIdx.x >> 6;
#pragma unroll
  for (int j = 0; j < 16; j++) {
    int kk = wr * 16 + j;
    tile[kk][lane] = fW4[(size_t)(k0 + kk) * 59392 + m0 + lane];
  }
  __syncthreads();
#pragma unroll
  for (int j = 0; j < 16; j++) {
    int mloc = wr * 16 + j;
    int m = m0 + mloc;
    int hh = m / 232, cc = m - hh * 232;
    W4T[((size_t)hh * CP + cc) * KA + k0 + lane] = f2bf(tile[lane][mloc]);
  }
}

// Prep: fill k'=256 (bias), k'=257..287 zeros, and c>=232 zero rows of W4T
__global__ __launch_bounds__(256) void k_prep_pad(const float* __restrict__ fb4,
                                                  short* __restrict__ W4T) {
  int idx = blockIdx.x * 256 + threadIdx.x;
  const int partA = 61440 * 32;
  if (idx < partA) {
    int row = idx >> 5, j = idx & 31;
    int hh = row / CP, cc = row - hh * CP;
    short v = 0;
    if (j == 0 && cc < 232) v = f2bf(fb4[hh * 232 + cc]);
    W4T[(size_t)row * KA + 256 + j] = v;
  } else {
    int t = idx - partA;
    int k = t & 255; t >>= 8;
    int cc = 232 + (t & 7); int hh = t >> 3;
    W4T[((size_t)hh * CP + cc) * KA + k] = 0;
  }
}

// Prep: tiled transpose f32 (K x Nn) -> bf16 out[n][k]
__global__ __launch_bounds__(256) void k_prep_wt(const float* __restrict__ in,
                                                 short* __restrict__ out,
                                                 int K, int Nn) {
  __shared__ float tile[64][65];
  int n0 = blockIdx.x * 64, k0 = blockIdx.y * 64;
  int lane = threadIdx.x & 63, wr = threadIdx.x >> 6;
#pragma unroll
  for (int j = 0; j < 16; j++) {
    int kk = wr * 16 + j;
    tile[kk][lane] = in[(size_t)(k0 + kk) * Nn + n0 + lane];
  }
  __syncthreads();
#pragma unroll
  for (int j = 0; j < 16; j++) {
    int nl = wr * 16 + j;
    out[(size_t)(n0 + nl) * K + k0 + lane] = f2bf(tile[lane][nl]);
  }
}

// Prep: static part of frag-major t3aug (k'=256 bias=1, 257..287 = 0)
__global__ __launch_bounds__(128) void k_prep_t3pad(short* __restrict__ t3aug) {
  int r = threadIdx.x;
  if (r < 128) {
    int base = ((r >> 4) * 9 + 8) * 64 + (r & 15);
#pragma unroll
    for (int q = 0; q < 4; q++)
#pragma unroll
      for (int j = 0; j < 8; j++)
        t3aug[(size_t)(base + q * 16) * 8 + j] = (q == 0 && j == 0) ? (short)0x3F80 : (short)0;
  }
}

// Prep: zero int region
__global__ __launch_bounds__(256) void k_prep_zero(int* __restrict__ p, int n) {
  int i = blockIdx.x * 256 + threadIdx.x;
  if (i < n) p[i] = 0;
}

// ---------------------------------------------------------------------------
// Persistent scan: 256 blocks x 512 threads. Per phase:
// S1 (blk<128, (m,j)): T1[m-rows, j*64 cols] = X@W1+fb1     [w1 frags in regs]
// S2 (blk<128, (m,n)): T2[m-rows, n*16 cols] = relu(LN1(T1))@W2+fb2
// S3 (blk<128, (m,n)): t3 slice -> frag-major packed bf16
// S4 (all 256, h=blk): z += scale*(t3 @ W4[h]).dX           [W4 in regs]
// Sync: last-producer-publishes single flag line; 1 polling thread/block.
// Consumers use agent-acquire fence (buffer_inv) + PLAIN cached loads, so
// intermediates are served from the local XCD L2 after one MALL fill.
// ---------------------------------------------------------------------------
__global__ __launch_bounds__(512, 1) void k_scan(
    const short* __restrict__ W1T, const float* __restrict__ fb1,
    const float* __restrict__ g1,  const float* __restrict__ be1,
    const short* __restrict__ W2T, const float* __restrict__ fb2,
    const float* __restrict__ g2,  const float* __restrict__ be2,
    const short* __restrict__ W3T, const float* __restrict__ fb3,
    const short* __restrict__ W4T,
    const float* __restrict__ dknot, const float* __restrict__ dmid,
    float* __restrict__ z, uint* __restrict__ Xu, uint* __restrict__ t3u,
    float* __restrict__ T1, float* __restrict__ T2,
    int* __restrict__ flags) {
  const int blk = blockIdx.x;
  const int tid = threadIdx.x;
  const int wave = tid >> 6, lane = tid & 63;
  const int lm = lane & 15, q = lane >> 4;
  const int m = (blk & 127) >> 4;   // row-group, blocks 0..127
  const int n = blk & 15;           // col-slice selector
  const int ks = wave >> 2, nwt = wave & 3;

  __shared__ short t3s[B * KA];          // 72 KB
  __shared__ float red2[8][256];         //  8 KB
  __shared__ float red4[8][128];         //  4 KB
  __shared__ float zcol[128];
  __shared__ float g1s[WMH], be1s[WMH];  //  8 KB (survive L2 invalidates)
  __shared__ float g2s[H], be2s[H];      //  2 KB
  __shared__ float fb1s[64];
  __shared__ float fb2s[16], fb3s[16];

  // flag/counter lines (16 ints each)
  int* cS1g = flags;                 // [8*NPH]
  int* fS1g = flags + 1008 * 16;
  int* cS2g = flags + 2016 * 16;
  int* fS2g = flags + 3024 * 16;
  int* cS3  = flags + 4032 * 16;     // [NPH]
  int* fS3  = flags + 4158 * 16;
  int* cS4  = flags + 4284 * 16;
  int* fS4  = flags + 4410 * 16;

  // persistent W4 B-fragments (all blocks; h = blk)
  const int nts = (wave < 7) ? 2 : 1;
  const int nt0 = wave * 2;
  short8 bfr[2][9];
  for (int t = 0; t < nts; t++) {
    const short* wp = W4T + ((size_t)blk * CP + (nt0 + t) * 16 + lm) * KA + q * 8;
#pragma unroll
    for (int kc = 0; kc < 9; kc++)
      bfr[t][kc] = *(const short8*)(wp + kc * 32);
  }
  // persistent MLP weight fragments (blocks 0..127)
  short8 w1f[4], w2f[4], w3f;
  if (blk < 128) {
    const short* p1 = W1T + ((size_t)(n * 64 + nwt * 16 + lm)) * H + ks * 128 + q * 8;
#pragma unroll
    for (int kc = 0; kc < 4; kc++) w1f[kc] = *(const short8*)(p1 + kc * 32);
    const short* p2 = W2T + ((size_t)(n * 16 + lm)) * WMH + wave * 128 + q * 8;
#pragma unroll
    for (int kc = 0; kc < 4; kc++) w2f[kc] = *(const short8*)(p2 + kc * 32);
    w3f = *(const short8*)(W3T + ((size_t)(n * 16 + lm)) * H + wave * 32 + q * 8);
  }
  // LDS-resident LN params and bias slices (read each phase; L2 gets inv'd)
  for (int i = tid; i < WMH; i += 512) { g1s[i] = g1[i]; be1s[i] = be1[i]; }
  for (int i = tid; i < H; i += 512)   { g2s[i] = g2[i]; be2s[i] = be2[i]; }
  if (tid < 64) fb1s[tid] = fb1[n * 64 + tid];
  if (tid < 16) { fb2s[tid] = fb2[n * 16 + tid]; fb3s[tid] = fb3[n * 16 + tid]; }
  if (tid < 128) zcol[tid] = z[(size_t)tid * H + blk];
  __syncthreads();

#pragma unroll 1
  for (int p = 0; p < NPH; p++) {
    const int seg = p >> 1, pm = p & 1;
    const float* dX = (pm ? dmid : dknot) + (size_t)seg * B * CP;
    const float scale = pm ? HSTEP : 0.5f * HSTEP;

    // ---- S1: T1[m-rows, n*64 cols] = X @ W1 + fb1 ----
    if (blk < 128) {
      if (p) waitflag(fS4 + (p - 1) * 16, 1);
      const uint* xp = Xu + (size_t)(m * 16 + lm) * H + ks * 128 + q * 8;
      uint4v xv[8];
      xv[0] = *(const uint4v*)(xp);
      xv[1] = *(const uint4v*)(xp + 4);
      xv[2] = *(const uint4v*)(xp + 32);
      xv[3] = *(const uint4v*)(xp + 36);
      xv[4] = *(const uint4v*)(xp + 64);
      xv[5] = *(const uint4v*)(xp + 68);
      xv[6] = *(const uint4v*)(xp + 96);
      xv[7] = *(const uint4v*)(xp + 100);
      f32x4 acc = {0.f, 0.f, 0.f, 0.f};
#pragma unroll
      for (int kc = 0; kc < 4; kc++) {
        short8 ah, al;
        unpk(xv[kc * 2], xv[kc * 2 + 1], ah, al);
        acc = MFMA16(ah, w1f[kc], acc);
        acc = MFMA16(al, w1f[kc], acc);
      }
#pragma unroll
      for (int r = 0; r < 4; r++) red2[wave][(q * 4 + r) * 16 + lm] = acc[r];
      __syncthreads();
      if (wave < 4) {
        int col = n * 64 + wave * 16 + lm;
        float fb = fb1s[wave * 16 + lm];
#pragma unroll
        for (int r = 0; r < 4; r++) {
          int idx = (q * 4 + r) * 16 + lm;
          float v = red2[wave][idx] + red2[wave + 4][idx] + fb;
          cstoref(T1 + (size_t)(m * 16 + q * 4 + r) * WMH + col, v);
        }
      }
      siggroup(cS1g + (m * NPH + p) * 16, 16, fS1g + (m * NPH + p) * 16);
    }

    // ---- S2: T2 slice = relu(LN1(T1)) @ W2 + fb2, group-local wait ----
    if (blk < 128) {
      waitflag(fS1g + (m * NPH + p) * 16, 1);
      const float* tp = T1 + (size_t)(m * 16 + lm) * WMH + wave * 128 + q * 8;
      f32x4 yv[8];
      yv[0] = *(const f32x4*)(tp);
      yv[1] = *(const f32x4*)(tp + 4);
      yv[2] = *(const f32x4*)(tp + 32);
      yv[3] = *(const f32x4*)(tp + 36);
      yv[4] = *(const f32x4*)(tp + 64);
      yv[5] = *(const f32x4*)(tp + 68);
      yv[6] = *(const f32x4*)(tp + 96);
      yv[7] = *(const f32x4*)(tp + 100);
      float s = 0.f, ss = 0.f;
#pragma unroll
      for (int i = 0; i < 8; i++)
#pragma unroll
        for (int e = 0; e < 4; e++) {
          float v = yv[i][e];
          s += v; ss += v * v;
        }
      s += __shfl_xor(s, 16); ss += __shfl_xor(ss, 16);
      s += __shfl_xor(s, 32); ss += __shfl_xor(ss, 32);
      if (q == 0) { red2[wave][lm] = s; red2[wave][16 + lm] = ss; }
      __syncthreads();
      float S = 0.f, SS = 0.f;
#pragma unroll
      for (int w = 0; w < 8; w++) { S += red2[w][lm]; SS += red2[w][16 + lm]; }
      float mean = S * (1.f / WMH);
      float var  = SS * (1.f / WMH) - mean * mean;
      float rsv  = rsqrtf(var + EPS);
      __syncthreads();
      f32x4 acc = {0.f, 0.f, 0.f, 0.f};
#pragma unroll
      for (int kc = 0; kc < 4; kc++) {
        int kg = wave * 128 + kc * 32 + q * 8;
        short8 ah, al;
#pragma unroll
        for (int jj = 0; jj < 8; jj++) {
          float v = yv[kc * 2 + (jj >> 2)][jj & 3];
          float a = fmaxf((v - mean) * rsv * g1s[kg + jj] + be1s[kg + jj], 0.f);
          short hi = f2bf(a);
          ah[jj] = hi;
          al[jj] = f2bf(a - bf2f(hi));
        }
        acc = MFMA16(ah, w2f[kc], acc);
        acc = MFMA16(al, w2f[kc], acc);
      }
#pragma unroll
      for (int r = 0; r < 4; r++) red2[wave][(q * 4 + r) * 16 + lm] = acc[r];
      __syncthreads();
      if (tid < 256) {
        int ri = tid >> 4, ci = tid & 15;
        float v = fb2s[ci];
#pragma unroll
        for (int w = 0; w < 8; w++) v += red2[w][tid];
        cstoref(T2 + (size_t)(m * 16 + ri) * H + n * 16 + ci, v);
      }
      siggroup(cS2g + (m * NPH + p) * 16, 16, fS2g + (m * NPH + p) * 16);
    }

    // ---- S3: t3 slice -> frag-major packed bf16, group-local wait ----
    if (blk < 128) {
      waitflag(fS2g + (m * NPH + p) * 16, 1);
      const float* tp = T2 + (size_t)(m * 16 + lm) * H + wave * 32 + q * 8;
      f32x4 u0 = *(const f32x4*)(tp);
      f32x4 u1 = *(const f32x4*)(tp + 4);
      float s = 0.f, ss = 0.f;
#pragma unroll
      for (int e = 0; e < 4; e++) {
        float v0 = u0[e], v1 = u1[e];
        s += v0 + v1; ss += v0 * v0 + v1 * v1;
      }
      s += __shfl_xor(s, 16); ss += __shfl_xor(ss, 16);
      s += __shfl_xor(s, 32); ss += __shfl_xor(ss, 32);
      if (q == 0) { red2[wave][lm] = s; red2[wave][16 + lm] = ss; }
      __syncthreads();
      float S = 0.f, SS = 0.f;
#pragma unroll
      for (int w = 0; w < 8; w++) { S += red2[w][lm]; SS += red2[w][16 + lm]; }
      float mean = S * (1.f / H);
      float var  = SS * (1.f / H) - mean * mean;
      float rsv  = rsqrtf(var + EPS);
      __syncthreads();
      int kg = wave * 32 + q * 8;
      short8 ah, al;
#pragma unroll
      for (int jj = 0; jj < 8; jj++) {
        float v = (jj < 4 ? u0[jj & 3] : u1[jj & 3]);
        float a = fmaxf((v - mean) * rsv * g2s[kg + jj] + be2s[kg + jj], 0.f);
        short hi = f2bf(a);
        ah[jj] = hi;
        al[jj] = f2bf(a - bf2f(hi));
      }
      f32x4 acc = {0.f, 0.f, 0.f, 0.f};
      acc = MFMA16(ah, w3f, acc);
      acc = MFMA16(al, w3f, acc);
#pragma unroll
      for (int r = 0; r < 4; r++) red2[wave][(q * 4 + r) * 16 + lm] = acc[r];
      __syncthreads();
      if (tid < 256) {
        int ri = tid >> 4, ci = tid & 15;
        float v = fb3s[ci];
#pragma unroll
        for (int w = 0; w < 8; w++) v += red2[w][tid];
        v = fmaxf(v, 0.f);
        float vo = __shfl_xor(v, 1);
        if ((ci & 1) == 0) {
          int kglob = n * 16 + ci;
          int d = (m * 9 + (kglob >> 5)) * 64 + ((kglob >> 3) & 3) * 16 + ri;
          uint u = ((uint)(unsigned short)f2bf(vo) << 16)
                 | (unsigned short)f2bf(v);
          cstoreu(t3u + d * 4 + ((kglob & 7) >> 1), u);
        }
      }
      siggroup(cS3 + p * 16, 128, fS3 + p * 16);
    }

    // ---- S4: all 256 blocks, h = blk ----
    {
      waitflag(fS3 + p * 16, 1);
      {
        const uint* tb = t3u + tid * 4;
        uint4v r0 = *(const uint4v*)(tb);
        uint4v r1 = *(const uint4v*)(tb + 2048);
        uint4v r2 = *(const uint4v*)(tb + 4096);
        uint4v r3 = *(const uint4v*)(tb + 6144);
        uint4v r4 = *(const uint4v*)(tb + 8192);
        uint4v r5 = *(const uint4v*)(tb + 10240);
        uint4v r6 = *(const uint4v*)(tb + 12288);
        uint4v r7 = *(const uint4v*)(tb + 14336);
        uint4v r8 = *(const uint4v*)(tb + 16384);
        *(uint4v*)(t3s + (size_t)(0 * 2048 + tid * 4) * 2) = r0;
        *(uint4v*)(t3s + (size_t)(1 * 2048 + tid * 4) * 2) = r1;
        *(uint4v*)(t3s + (size_t)(2 * 2048 + tid * 4) * 2) = r2;
        *(uint4v*)(t3s + (size_t)(3 * 2048 + tid * 4) * 2) = r3;
        *(uint4v*)(t3s + (size_t)(4 * 2048 + tid * 4) * 2) = r4;
        *(uint4v*)(t3s + (size_t)(5 * 2048 + tid * 4) * 2) = r5;
        *(uint4v*)(t3s + (size_t)(6 * 2048 + tid * 4) * 2) = r6;
        *(uint4v*)(t3s + (size_t)(7 * 2048 + tid * 4) * 2) = r7;
        *(uint4v*)(t3s + (size_t)(8 * 2048 + tid * 4) * 2) = r8;
      }
      __syncthreads();
      for (int mm = 0; mm < 8; mm++) {
        short8 afr[9];
#pragma unroll
        for (int kc = 0; kc < 9; kc++)
          afr[kc] = *(const short8*)(t3s + (size_t)((mm * 9 + kc) * 64 + lane) * 8);
        f32x4 acc0 = {0.f, 0.f, 0.f, 0.f}, acc1 = {0.f, 0.f, 0.f, 0.f};
#pragma unroll
        for (int kc = 0; kc < 9; kc++) {
          acc0 = MFMA16(afr[kc], bfr[0][kc], acc0);
          if (nts > 1) acc1 = MFMA16(afr[kc], bfr[1][kc], acc1);
        }
        float part[4];
#pragma unroll
        for (int r = 0; r < 4; r++) {
          int row = mm * 16 + q * 4 + r;
          float pv = acc0[r] * dX[(size_t)row * CP + nt0 * 16 + lm];
          if (nts > 1) pv += acc1[r] * dX[(size_t)row * CP + (nt0 + 1) * 16 + lm];
          part[r] = pv;
        }
#pragma unroll
        for (int r = 0; r < 4; r++) {
          part[r] += __shfl_xor(part[r], 1);
          part[r] += __shfl_xor(part[r], 2);
          part[r] += __shfl_xor(part[r], 4);
          part[r] += __shfl_xor(part[r], 8);
        }
        if (lm == 0) {
#pragma unroll
          for (int r = 0; r < 4; r++) red4[wave][mm * 16 + q * 4 + r] = part[r];
        }
      }
      __syncthreads();
      if (tid < 128) {
        int row = tid;
        float s = 0.f;
#pragma unroll
        for (int w = 0; w < 8; w++) s += red4[w][row];
        float zo = zcol[row] + scale * s;
        if (pm) zcol[row] = zo;
        if (p == NPH - 1) z[(size_t)row * H + blk] = zo;
        short hi = f2bf(zo);
        short lo = f2bf(zo - bf2f(hi));
        cstoreu(Xu + (size_t)row * H + blk,
                ((uint)(unsigned short)hi << 16) | (unsigned short)lo);
      }
      siggroup(cS4 + p * 16, 256, fS4 + p * 16);
    }
  }
}

// ---------------------------------------------------------------------------
// Kernel 6: output heads
// ---------------------------------------------------------------------------
__global__ __launch_bounds__(256) void k_final(const float* __restrict__ z,
    const float* __restrict__ yW1, const float* __restrict__ yb1,
    const float* __restrict__ yW2, const float* __restrict__ yb2,
    const float* __restrict__ zW1, const float* __restrict__ zb1,
    const float* __restrict__ zW2, const float* __restrict__ zb2,
    float* __restrict__ out) {
  __shared__ float ht[H];
  __shared__ float ry[128];
  __shared__ float rz[H];
  int b = blockIdx.x, tid = threadIdx.x;
  ht[tid] = z[(size_t)b * H + tid];
  __syncthreads();
  if (tid < 128) {
    float s = yb1[tid];
    for (int k = 0; k < H; k++) s += ht[k] * yW1[k * 128 + tid];
    ry[tid] = fmaxf(s, 0.f);
  }
  {
    float s = zb1[tid];
    for (int k = 0; k < H; k++) s += ht[k] * zW1[k * H + tid];
    rz[tid] = fmaxf(s, 0.f);
  }
  __syncthreads();
  if (tid < 64) {
    float sv = ry[tid] * yW2[tid] + ry[tid + 64] * yW2[tid + 64];
    for (int off = 32; off > 0; off >>= 1) sv += __shfl_down(sv, off);
    if (tid == 0) out[b] = sv + yb2[0];
  }
  if (tid < D) {
    float s = zb2[tid];
    for (int k = 0; k < H; k++) s += rz[k] * zW2[k * D + tid];
    out[B + b * D + tid] = s;
  }
  out[B + B * D + (size_t)b * H + tid] = ht[tid];
}

// ---------------------------------------------------------------------------
extern "C" void kernel_launch(void* const* d_in, const int* in_sizes, int n_in,
                              void* d_out, int out_size, void* d_ws, size_t ws_size,
                              hipStream_t stream) {
  const float* x   = (const float*)d_in[0];
  const float* hW1 = (const float*)d_in[1];
  const float* hb1 = (const float*)d_in[2];
  const float* hW2 = (const float*)d_in[3];
  const float* hb2 = (const float*)d_in[4];
  const float* fW1 = (const float*)d_in[5];
  const float* fb1 = (const float*)d_in[6];
  const float* g1  = (const float*)d_in[7];
  const float* be1 = (const float*)d_in[8];
  const float* fW2 = (const float*)d_in[9];
  const float* fb2 = (const float*)d_in[10];
  const float* g2  = (const float*)d_in[11];
  const float* be2 = (const float*)d_in[12];
  const float* fW3 = (const float*)d_in[13];
  const float* fb3 = (const float*)d_in[14];
  const float* fW4 = (const float*)d_in[15];
  const float* fb4 = (const float*)d_in[16];
  const float* yW1 = (const float*)d_in[17];
  const float* yb1 = (const float*)d_in[18];
  const float* yW2 = (const float*)d_in[19];
  const float* yb2 = (const float*)d_in[20];
  const float* zW1 = (const float*)d_in[21];
  const float* zb1 = (const float*)d_in[22];
  const float* zW2 = (const float*)d_in[23];
  const float* zb2 = (const float*)d_in[24];
  const float* sg  = (const float*)d_in[25];
  const float* sb  = (const float*)d_in[26];

  float* ws     = (float*)d_ws;
  float* dknot  = ws;                               // 1,935,360 f
  float* dmid   = dknot + (size_t)NSEG * B * CP;    // 1,935,360 f
  float* z      = dmid + (size_t)NSEG * B * CP;     // 32,768 f
  float* T1     = z + B * H;                        // 131,072 f
  float* T2     = T1 + B * WMH;                     // 32,768 f
  uint* Xu      = (uint*)(T2 + B * H);              // 32,768 u
  uint* t3u     = Xu + B * H;                       // 18,432 u
  int* flags    = (int*)(t3u + B * KA / 2);         // 72,576 i (4536 lines)
  short* w1T    = (short*)(flags + 72576);          // 262,144 s
  short* w2T    = w1T + H * WMH;                    // 262,144 s
  short* w3T    = w2T + H * WMH;                    // 65,536 s
  short* W4T    = w3T + H * H;                      // 17,694,720 s
  float* y      = (float*)W4T;                      // temp alias (dead before W4T built)

  hipLaunchKernelGGL(k_logsig, dim3(B), dim3(256), 0, stream, x, sg, sb, y);
  hipLaunchKernelGGL(k_spline, dim3(B), dim3(256), 0, stream, y, dknot, dmid);
  hipLaunchKernelGGL(k_h0,     dim3(B), dim3(256), 0, stream, x, hW1, hb1, hW2, hb2, z, Xu);
  hipLaunchKernelGGL(k_prep_t,   dim3(928, 4), dim3(256), 0, stream, fW4, W4T);
  hipLaunchKernelGGL(k_prep_pad, dim3(9728),   dim3(256), 0, stream, fb4, W4T);
  hipLaunchKernelGGL(k_prep_wt,  dim3(16, 4),  dim3(256), 0, stream, fW1, w1T, H, WMH);
  hipLaunchKernelGGL(k_prep_wt,  dim3(4, 16),  dim3(256), 0, stream, fW2, w2T, WMH, H);
  hipLaunchKernelGGL(k_prep_wt,  dim3(4, 4),   dim3(256), 0, stream, fW3, w3T, H, H);
  hipLaunchKernelGGL(k_prep_t3pad, dim3(1), dim3(128), 0, stream, (short*)t3u);
  hipLaunchKernelGGL(k_prep_zero, dim3(284), dim3(256), 0, stream, flags, 72576);

  void* args[] = {
    (void*)&w1T, (void*)&fb1, (void*)&g1, (void*)&be1,
    (void*)&w2T, (void*)&fb2, (void*)&g2, (void*)&be2,
    (void*)&w3T, (void*)&fb3, (void*)&W4T,
    (void*)&dknot, (void*)&dmid,
    (void*)&z, (void*)&Xu, (void*)&t3u,
    (void*)&T1, (void*)&T2, (void*)&flags
  };
  hipLaunchCooperativeKernel((const void*)k_scan, dim3(256), dim3(512), args, 0, stream);

  hipLaunchKernelGGL(k_final, dim3(B), dim3(256), 0, stream, z,
                     yW1, yb1, yW2, yb2, zW1, zb1, zW2, zb2, (float*)d_out);
}

// Round 4
// 4610.841 us; speedup vs baseline: 1.0502x; 1.0502x over previous
//
#include <hip/hip_runtime.h>

#define B 128
#define N 64
#define D 20
#define H 256
#define WMH 1024
#define CAUG 21
#define SIG 231
#define C 232
#define CP 240          // padded C
#define KA 288          // augmented K (256 + bias row + pad)
#define NSEG 63
#define NPH 126
#define HSTEP (1.0f/63.0f)
#define EPS 1e-5f

typedef __attribute__((ext_vector_type(8))) short short8;
typedef __attribute__((ext_vector_type(4))) float f32x4;
typedef __attribute__((ext_vector_type(4))) unsigned int uint4v;
typedef __attribute__((ext_vector_type(2))) int int2v;
typedef __attribute__((ext_vector_type(4))) int int4v;
typedef unsigned int uint;

__device__ inline short f2bf(float f) {
  uint u = __float_as_uint(f);
  uint r = (u + 0x7fffu + ((u >> 16) & 1u)) >> 16;
  return (short)r;
}
__device__ inline float bf2f(short h) {
  return __uint_as_float(((uint)(unsigned short)h) << 16);
}
#define MFMA16(a, b, c) __builtin_amdgcn_mfma_f32_16x16x32_bf16((a), (b), (c), 0, 0, 0)

// --- relaxed agent-scope scalar coherent ops (write-through to MALL)
__device__ inline void cstoreu(uint* p, uint v) {
  __hip_atomic_store(p, v, __ATOMIC_RELAXED, __HIP_MEMORY_SCOPE_AGENT);
}
__device__ inline void cstoref(float* p, float v) {
  __hip_atomic_store(p, v, __ATOMIC_RELAXED, __HIP_MEMORY_SCOPE_AGENT);
}
__device__ inline void cstorei(int* p, int v) {
  __hip_atomic_store(p, v, __ATOMIC_RELAXED, __HIP_MEMORY_SCOPE_AGENT);
}

// --- batched coherent vector loads (sc0 sc1 = read through to coherence point)
#define CLOAD8(r0,r1,r2,r3,r4,r5,r6,r7,addr)                                   \
  asm volatile("global_load_dwordx4 %0, %8, off sc0 sc1\n\t"                   \
               "global_load_dwordx4 %1, %8, off offset:16 sc0 sc1\n\t"         \
               "global_load_dwordx4 %2, %8, off offset:128 sc0 sc1\n\t"        \
               "global_load_dwordx4 %3, %8, off offset:144 sc0 sc1\n\t"        \
               "global_load_dwordx4 %4, %8, off offset:256 sc0 sc1\n\t"        \
               "global_load_dwordx4 %5, %8, off offset:272 sc0 sc1\n\t"        \
               "global_load_dwordx4 %6, %8, off offset:384 sc0 sc1\n\t"        \
               "global_load_dwordx4 %7, %8, off offset:400 sc0 sc1\n\t"        \
               "s_waitcnt vmcnt(0)"                                            \
               : "=&v"(r0), "=&v"(r1), "=&v"(r2), "=&v"(r3),                   \
                 "=&v"(r4), "=&v"(r5), "=&v"(r6), "=&v"(r7)                    \
               : "v"(addr)                                                     \
               : "memory")

#define CLOAD2(r0,r1,addr)                                                     \
  asm volatile("global_load_dwordx4 %0, %2, off sc0 sc1\n\t"                   \
               "global_load_dwordx4 %1, %2, off offset:16 sc0 sc1\n\t"         \
               "s_waitcnt vmcnt(0)"                                            \
               : "=&v"(r0), "=&v"(r1) : "v"(addr) : "memory")

// 9 x dwordx4 (full t3 stripe) with ONE wait
#define CLOAD9(r0,r1,r2,r3,r4,r5,r6,r7,r8,a0,a1,a2,a3,a4,a5,a6,a7,a8)          \
  asm volatile("global_load_dwordx4 %0, %9, off sc0 sc1\n\t"                   \
               "global_load_dwordx4 %1, %10, off sc0 sc1\n\t"                  \
               "global_load_dwordx4 %2, %11, off sc0 sc1\n\t"                  \
               "global_load_dwordx4 %3, %12, off sc0 sc1\n\t"                  \
               "global_load_dwordx4 %4, %13, off sc0 sc1\n\t"                  \
               "global_load_dwordx4 %5, %14, off sc0 sc1\n\t"                  \
               "global_load_dwordx4 %6, %15, off sc0 sc1\n\t"                  \
               "global_load_dwordx4 %7, %16, off sc0 sc1\n\t"                  \
               "global_load_dwordx4 %8, %17, off sc0 sc1\n\t"                  \
               "s_waitcnt vmcnt(0)"                                            \
               : "=&v"(r0), "=&v"(r1), "=&v"(r2), "=&v"(r3), "=&v"(r4),        \
                 "=&v"(r5), "=&v"(r6), "=&v"(r7), "=&v"(r8)                    \
               : "v"(a0), "v"(a1), "v"(a2), "v"(a3), "v"(a4), "v"(a5),         \
                 "v"(a6), "v"(a7), "v"(a8)                                     \
               : "memory")

// ---------------------------------------------------------------------------
// Per-producer epoch flags (monotone, zeroed once at launch, NO atomics).
// Producer: workgroup-release fence (drains own vmcnt) + barrier, then
// thread 0 stores epoch to the producer's OWN word (write-through).
// Consumer: wave 0 wide-polls all producer words in ONE parallel MALL
// round-trip per iteration; other waves wait at the barrier.
// ---------------------------------------------------------------------------
__device__ inline void post(int* w, int v) {
  __builtin_amdgcn_fence(__ATOMIC_RELEASE, "workgroup");   // vmcnt drain
  __syncthreads();
  if (threadIdx.x == 0) cstorei(w, v);
}
__device__ inline void poll16(const int* f, int tgt) {   // 16 producer words
  if (threadIdx.x < 64) {
    const int* p = f + (threadIdx.x & 15);
    for (;;) {
      int v;
      asm volatile("global_load_dword %0, %1, off sc0 sc1\n\ts_waitcnt vmcnt(0)"
                   : "=v"(v) : "v"(p) : "memory");
      if (__all(v >= tgt)) break;
      __builtin_amdgcn_s_sleep(1);
    }
  }
  __builtin_amdgcn_fence(__ATOMIC_ACQUIRE, "workgroup");
  __syncthreads();
}
__device__ inline void poll128(const int* f, int tgt) {  // 128 producer words
  if (threadIdx.x < 64) {
    const int* p = f + threadIdx.x * 2;
    for (;;) {
      int2v v;
      asm volatile("global_load_dwordx2 %0, %1, off sc0 sc1\n\ts_waitcnt vmcnt(0)"
                   : "=v"(v) : "v"(p) : "memory");
      if (__all(v[0] >= tgt && v[1] >= tgt)) break;
      __builtin_amdgcn_s_sleep(1);
    }
  }
  __builtin_amdgcn_fence(__ATOMIC_ACQUIRE, "workgroup");
  __syncthreads();
}
__device__ inline void poll256(const int* f, int tgt) {  // 256 producer words
  if (threadIdx.x < 64) {
    const int* p = f + threadIdx.x * 4;
    for (;;) {
      int4v v;
      asm volatile("global_load_dwordx4 %0, %1, off sc0 sc1\n\ts_waitcnt vmcnt(0)"
                   : "=v"(v) : "v"(p) : "memory");
      if (__all(v[0] >= tgt && v[1] >= tgt && v[2] >= tgt && v[3] >= tgt)) break;
      __builtin_amdgcn_s_sleep(1);
    }
  }
  __builtin_amdgcn_fence(__ATOMIC_ACQUIRE, "workgroup");
  __syncthreads();
}

__device__ inline void unpk(uint4v a, uint4v b, short8& ah, short8& al) {
#pragma unroll
  for (int e = 0; e < 4; e++) {
    ah[e]     = (short)(a[e] >> 16); al[e]     = (short)(a[e] & 0xffffu);
    ah[4 + e] = (short)(b[e] >> 16); al[4 + e] = (short)(b[e] & 0xffffu);
  }
}

// ---------------------------------------------------------------------------
// Kernel 1: depth-2 log-signature + LayerNorm -> y (B,N,C)
// ---------------------------------------------------------------------------
__global__ __launch_bounds__(256) void k_logsig(const float* __restrict__ x,
                                                const float* __restrict__ sg,
                                                const float* __restrict__ sb,
                                                float* __restrict__ y) {
  __shared__ float yb[N][C];
  int b = blockIdx.x, tid = threadIdx.x;
  for (int ii = tid; ii < N * CAUG; ii += 256) {
    int n = ii / CAUG, j = ii % CAUG;
    float v = (j == 0) ? (n * (1.0f / 63.0f)) : x[(b * N + n) * D + (j - 1)];
    yb[n][1 + j] = v;
  }
  __syncthreads();
  if (tid < 210) {
    int i = 0, rem = tid;
    while (rem >= (CAUG - 1) - i) { rem -= (CAUG - 1) - i; i++; }
    int j = i + 1 + rem;
    float acc = 0.f, pi_prev = 0.f, pj_prev = 0.f;
    for (int n = 0; n < N; n++) {
      float pi = yb[n][1 + i], pj = yb[n][1 + j];
      float di = pi - pi_prev, dj = pj - pj_prev;
      acc += 0.5f * (pi_prev * dj - di * pj_prev);
      yb[n][1 + CAUG + tid] = acc;
      pi_prev = pi; pj_prev = pj;
    }
  }
  __syncthreads();
  int w = tid >> 6, l = tid & 63;
  for (int n = w; n < N; n += 4) {
    float s1 = 0.f, s2 = 0.f;
    for (int s = l; s < SIG; s += 64) { float v = yb[n][1 + s]; s1 += v; s2 += v * v; }
    for (int off = 32; off > 0; off >>= 1) { s1 += __shfl_down(s1, off); s2 += __shfl_down(s2, off); }
    s1 = __shfl(s1, 0); s2 = __shfl(s2, 0);
    float mean = s1 * (1.0f / SIG);
    float var  = s2 * (1.0f / SIG) - mean * mean;
    float rs = rsqrtf(var + EPS);
    float* yrow = y + ((size_t)b * N + n) * C;
    if (l == 0) yrow[0] = n * (1.0f / 63.0f);
    for (int s = l; s < SIG; s += 64)
      yrow[1 + s] = (yb[n][1 + s] - mean) * rs * sg[s] + sb[s];
  }
}

// ---------------------------------------------------------------------------
// Kernel 2: natural cubic spline -> d_knot, d_mid (NSEG, B, CP) zero-padded
// ---------------------------------------------------------------------------
__global__ __launch_bounds__(256) void k_spline(const float* __restrict__ y,
                                                float* __restrict__ dknot,
                                                float* __restrict__ dmid) {
  __shared__ float yb[N * C];
  __shared__ float cp_s[62], id_s[62];
  int b = blockIdx.x, tid = threadIdx.x;
  for (int ii = tid; ii < N * C; ii += 256) yb[ii] = y[(size_t)b * N * C + ii];
  if (tid == 0) {
    const float a = HSTEP / 6.f, bb = 2.f * HSTEP / 3.f;
    float id0 = 1.f / bb; id_s[0] = id0; cp_s[0] = a * id0;
    for (int j = 1; j < 62; j++) {
      float den = bb - a * cp_s[j - 1];
      float idj = 1.f / den; id_s[j] = idj; cp_s[j] = a * idj;
    }
  }
  __syncthreads();
  int c = tid;
  if (c >= 232 && c < CP) {
    for (int n = 0; n < NSEG; n++) {
      dknot[((size_t)n * B + b) * CP + c] = 0.f;
      dmid [((size_t)n * B + b) * CP + c] = 0.f;
    }
  } else if (c < 232) {
    const float a = HSTEP / 6.f;
    float dp[62];
    dp[0] = (yb[2 * C + c] - 2.f * yb[1 * C + c] + yb[0 * C + c]) * 63.0f * id_s[0];
#pragma unroll
    for (int j = 1; j < 62; j++) {
      float rj = (yb[(j + 2) * C + c] - 2.f * yb[(j + 1) * C + c] + yb[j * C + c]) * 63.0f;
      dp[j] = (rj - a * dp[j - 1]) * id_s[j];
    }
#pragma unroll
    for (int j = 60; j >= 0; j--) dp[j] -= cp_s[j] * dp[j + 1];
#pragma unroll
    for (int n = 0; n < NSEG; n++) {
      float Mn  = (n == 0)  ? 0.f : dp[n - 1];
      float Mn1 = (n == 62) ? 0.f : dp[n];
      float dy = (yb[(n + 1) * C + c] - yb[n * C + c]) * 63.0f;
      dknot[((size_t)n * B + b) * CP + c] = dy - (HSTEP / 6.f)  * (2.f * Mn + Mn1);
      dmid [((size_t)n * B + b) * CP + c] = dy + (HSTEP / 24.f) * (Mn - Mn1);
    }
  }
}

// ---------------------------------------------------------------------------
// Kernel 3: initial hidden state -> z (f32) and Xu (packed hi|lo bf16)
// ---------------------------------------------------------------------------
__global__ __launch_bounds__(256) void k_h0(const float* __restrict__ x,
                                            const float* __restrict__ hW1,
                                            const float* __restrict__ hb1,
                                            const float* __restrict__ hW2,
                                            const float* __restrict__ hb2,
                                            float* __restrict__ z,
                                            uint* __restrict__ Xu) {
  __shared__ float r[H];
  int b = blockIdx.x, tid = threadIdx.x;
  float s = hb1[tid];
#pragma unroll
  for (int d = 0; d < D; d++) s += x[(size_t)(b * N) * D + d] * hW1[d * H + tid];
  r[tid] = fmaxf(s, 0.f);
  __syncthreads();
  float s2 = hb2[tid];
  for (int k = 0; k < H; k++) s2 += r[k] * hW2[k * H + tid];
  z[b * H + tid] = s2;
  short hi = f2bf(s2);
  short lo = f2bf(s2 - bf2f(hi));
  Xu[b * H + tid] = ((uint)(unsigned short)hi << 16) | (unsigned short)lo;
}

// ---------------------------------------------------------------------------
// Prep: transpose fW4 (256 x 59392) f32 -> W4T [h*240+c][288] bf16
// ---------------------------------------------------------------------------
__global__ __launch_bounds__(256) void k_prep_t(const float* __restrict__ fW4,
                                                short* __restrict__ W4T) {
  __shared__ float tile[64][65];
  int m0 = blockIdx.x * 64, k0 = blockIdx.y * 64;
  int lane = threadIdx.x & 63, wr = threadIdx.x >> 6;
#pragma unroll
  for (int j = 0; j < 16; j++) {
    int kk = wr * 16 + j;
    tile[kk][lane] = fW4[(size_t)(k0 + kk) * 59392 + m0 + lane];
  }
  __syncthreads();
#pragma unroll
  for (int j = 0; j < 16; j++) {
    int mloc = wr * 16 + j;
    int m = m0 + mloc;
    int hh = m / 232, cc = m - hh * 232;
    W4T[((size_t)hh * CP + cc) * KA + k0 + lane] = f2bf(tile[lane][mloc]);
  }
}

// Prep: fill k'=256 (bias), k'=257..287 zeros, and c>=232 zero rows of W4T
__global__ __launch_bounds__(256) void k_prep_pad(const float* __restrict__ fb4,
                                                  short* __restrict__ W4T) {
  int idx = blockIdx.x * 256 + threadIdx.x;
  const int partA = 61440 * 32;
  if (idx < partA) {
    int row = idx >> 5, j = idx & 31;
    int hh = row / CP, cc = row - hh * CP;
    short v = 0;
    if (j == 0 && cc < 232) v = f2bf(fb4[hh * 232 + cc]);
    W4T[(size_t)row * KA + 256 + j] = v;
  } else {
    int t = idx - partA;
    int k = t & 255; t >>= 8;
    int cc = 232 + (t & 7); int hh = t >> 3;
    W4T[((size_t)hh * CP + cc) * KA + k] = 0;
  }
}

// Prep: tiled transpose f32 (K x Nn) -> bf16 out[n][k]
__global__ __launch_bounds__(256) void k_prep_wt(const float* __restrict__ in,
                                                 short* __restrict__ out,
                                                 int K, int Nn) {
  __shared__ float tile[64][65];
  int n0 = blockIdx.x * 64, k0 = blockIdx.y * 64;
  int lane = threadIdx.x & 63, wr = threadIdx.x >> 6;
#pragma unroll
  for (int j = 0; j < 16; j++) {
    int kk = wr * 16 + j;
    tile[kk][lane] = in[(size_t)(k0 + kk) * Nn + n0 + lane];
  }
  __syncthreads();
#pragma unroll
  for (int j = 0; j < 16; j++) {
    int nl = wr * 16 + j;
    out[(size_t)(n0 + nl) * K + k0 + lane] = f2bf(tile[lane][nl]);
  }
}

// Prep: static part of frag-major t3aug (k'=256 bias=1, 257..287 = 0)
__global__ __launch_bounds__(128) void k_prep_t3pad(short* __restrict__ t3aug) {
  int r = threadIdx.x;
  if (r < 128) {
    int base = ((r >> 4) * 9 + 8) * 64 + (r & 15);
#pragma unroll
    for (int q = 0; q < 4; q++)
#pragma unroll
      for (int j = 0; j < 8; j++)
        t3aug[(size_t)(base + q * 16) * 8 + j] = (q == 0 && j == 0) ? (short)0x3F80 : (short)0;
  }
}

// Prep: zero int region
__global__ __launch_bounds__(256) void k_prep_zero(int* __restrict__ p, int n) {
  int i = blockIdx.x * 256 + threadIdx.x;
  if (i < n) p[i] = 0;
}

// ---------------------------------------------------------------------------
// Persistent scan: 256 blocks x 512 threads. Per phase:
// S1 (blk<128, (m,n)): T1[m-rows, n*64 cols] = X@W1+fb1     [w1 frags in regs]
// S2 (blk<128, (m,n)): T2[m-rows, n*16 cols] = relu(LN1(T1))@W2+fb2
// S3 (blk<128, (m,n)): t3 slice -> frag-major packed bf16
// S4 (all 256, h=blk): z += scale*(t3 @ W4[h]).dX           [W4 in regs]
// Sync: per-producer epoch flags (no atomics) + wave-parallel wide polls.
// Data: sc0sc1 write-through stores / read-through loads (MALL-coherent).
// ---------------------------------------------------------------------------
__global__ __launch_bounds__(512, 1) void k_scan(
    const short* __restrict__ W1T, const float* __restrict__ fb1,
    const float* __restrict__ g1,  const float* __restrict__ be1,
    const short* __restrict__ W2T, const float* __restrict__ fb2,
    const float* __restrict__ g2,  const float* __restrict__ be2,
    const short* __restrict__ W3T, const float* __restrict__ fb3,
    const short* __restrict__ W4T,
    const float* __restrict__ dknot, const float* __restrict__ dmid,
    float* __restrict__ z, uint* __restrict__ Xu, uint* __restrict__ t3u,
    float* __restrict__ T1, float* __restrict__ T2,
    int* __restrict__ flags) {
  const int blk = blockIdx.x;
  const int tid = threadIdx.x;
  const int wave = tid >> 6, lane = tid & 63;
  const int lm = lane & 15, q = lane >> 4;
  const int m = (blk & 127) >> 4;   // row-group, blocks 0..127
  const int n = blk & 15;           // col-slice selector
  const int ks = wave >> 2, nwt = wave & 3;

  __shared__ short t3s[B * KA];          // 72 KB
  __shared__ float red2[8][256];         //  8 KB
  __shared__ float red4[8][128];         //  4 KB
  __shared__ float zcol[128];
  __shared__ float g1s[WMH], be1s[WMH];  //  8 KB
  __shared__ float g2s[H], be2s[H];      //  2 KB
  __shared__ float fb1s[64];
  __shared__ float fb2s[16], fb3s[16];

  // per-producer epoch arrays (int each, zeroed at launch)
  int* eS1 = flags;            // [128]  (m*16+n)
  int* eS2 = flags + 128;      // [128]
  int* eS3 = flags + 256;      // [128]
  int* eS4 = flags + 384;      // [256]  (blk)   16B-aligned

  // persistent W4 B-fragments (all blocks; h = blk)
  const int nts = (wave < 7) ? 2 : 1;
  const int nt0 = wave * 2;
  short8 bfr[2][9];
  for (int t = 0; t < nts; t++) {
    const short* wp = W4T + ((size_t)blk * CP + (nt0 + t) * 16 + lm) * KA + q * 8;
#pragma unroll
    for (int kc = 0; kc < 9; kc++)
      bfr[t][kc] = *(const short8*)(wp + kc * 32);
  }
  // persistent MLP weight fragments (blocks 0..127)
  short8 w1f[4], w2f[4], w3f;
  if (blk < 128) {
    const short* p1 = W1T + ((size_t)(n * 64 + nwt * 16 + lm)) * H + ks * 128 + q * 8;
#pragma unroll
    for (int kc = 0; kc < 4; kc++) w1f[kc] = *(const short8*)(p1 + kc * 32);
    const short* p2 = W2T + ((size_t)(n * 16 + lm)) * WMH + wave * 128 + q * 8;
#pragma unroll
    for (int kc = 0; kc < 4; kc++) w2f[kc] = *(const short8*)(p2 + kc * 32);
    w3f = *(const short8*)(W3T + ((size_t)(n * 16 + lm)) * H + wave * 32 + q * 8);
  }
  // LDS-resident LN params and bias slices
  for (int i = tid; i < WMH; i += 512) { g1s[i] = g1[i]; be1s[i] = be1[i]; }
  for (int i = tid; i < H; i += 512)   { g2s[i] = g2[i]; be2s[i] = be2[i]; }
  if (tid < 64) fb1s[tid] = fb1[n * 64 + tid];
  if (tid < 16) { fb2s[tid] = fb2[n * 16 + tid]; fb3s[tid] = fb3[n * 16 + tid]; }
  if (tid < 128) zcol[tid] = z[(size_t)tid * H + blk];
  __syncthreads();

#pragma unroll 1
  for (int p = 0; p < NPH; p++) {
    const int seg = p >> 1, pm = p & 1;
    const float* dX = (pm ? dmid : dknot) + (size_t)seg * B * CP;
    const float scale = pm ? HSTEP : 0.5f * HSTEP;

    if (blk < 128) {
      // ---- S1: T1[m-rows, n*64 cols] = X @ W1 + fb1 ----
      if (p) poll256(eS4, p);
      const uint* xp = Xu + (size_t)(m * 16 + lm) * H + ks * 128 + q * 8;
      uint4v xv[8];
      CLOAD8(xv[0], xv[1], xv[2], xv[3], xv[4], xv[5], xv[6], xv[7], xp);
      {
        f32x4 acc = {0.f, 0.f, 0.f, 0.f};
#pragma unroll
        for (int kc = 0; kc < 4; kc++) {
          short8 ah, al;
          unpk(xv[kc * 2], xv[kc * 2 + 1], ah, al);
          acc = MFMA16(ah, w1f[kc], acc);
          acc = MFMA16(al, w1f[kc], acc);
        }
#pragma unroll
        for (int r = 0; r < 4; r++) red2[wave][(q * 4 + r) * 16 + lm] = acc[r];
      }
      __syncthreads();
      if (wave < 4) {
        int col = n * 64 + wave * 16 + lm;
        float fb = fb1s[wave * 16 + lm];
#pragma unroll
        for (int r = 0; r < 4; r++) {
          int idx = (q * 4 + r) * 16 + lm;
          float v = red2[wave][idx] + red2[wave + 4][idx] + fb;
          cstoref(T1 + (size_t)(m * 16 + q * 4 + r) * WMH + col, v);
        }
      }
      post(eS1 + m * 16 + n, p + 1);

      // ---- S2: T2 slice = relu(LN1(T1)) @ W2 + fb2, group-local wait ----
      poll16(eS1 + m * 16, p + 1);
      const float* tp = T1 + (size_t)(m * 16 + lm) * WMH + wave * 128 + q * 8;
      uint4v yv[8];
      CLOAD8(yv[0], yv[1], yv[2], yv[3], yv[4], yv[5], yv[6], yv[7], tp);
      {
        float s = 0.f, ss = 0.f;
#pragma unroll
        for (int i = 0; i < 8; i++)
#pragma unroll
          for (int e = 0; e < 4; e++) {
            float v = __uint_as_float(yv[i][e]);
            s += v; ss += v * v;
          }
        s += __shfl_xor(s, 16); ss += __shfl_xor(ss, 16);
        s += __shfl_xor(s, 32); ss += __shfl_xor(ss, 32);
        if (q == 0) { red2[wave][lm] = s; red2[wave][16 + lm] = ss; }
        __syncthreads();
        float S = 0.f, SS = 0.f;
#pragma unroll
        for (int w = 0; w < 8; w++) { S += red2[w][lm]; SS += red2[w][16 + lm]; }
        float mean = S * (1.f / WMH);
        float var  = SS * (1.f / WMH) - mean * mean;
        float rsv  = rsqrtf(var + EPS);
        __syncthreads();
        f32x4 acc = {0.f, 0.f, 0.f, 0.f};
#pragma unroll
        for (int kc = 0; kc < 4; kc++) {
          int kg = wave * 128 + kc * 32 + q * 8;
          short8 ah, al;
#pragma unroll
          for (int jj = 0; jj < 8; jj++) {
            float v = __uint_as_float(yv[kc * 2 + (jj >> 2)][jj & 3]);
            float a = fmaxf((v - mean) * rsv * g1s[kg + jj] + be1s[kg + jj], 0.f);
            short hi = f2bf(a);
            ah[jj] = hi;
            al[jj] = f2bf(a - bf2f(hi));
          }
          acc = MFMA16(ah, w2f[kc], acc);
          acc = MFMA16(al, w2f[kc], acc);
        }
#pragma unroll
        for (int r = 0; r < 4; r++) red2[wave][(q * 4 + r) * 16 + lm] = acc[r];
      }
      __syncthreads();
      if (tid < 256) {
        int ri = tid >> 4, ci = tid & 15;
        float v = fb2s[ci];
#pragma unroll
        for (int w = 0; w < 8; w++) v += red2[w][tid];
        cstoref(T2 + (size_t)(m * 16 + ri) * H + n * 16 + ci, v);
      }
      post(eS2 + m * 16 + n, p + 1);

      // ---- S3: t3 slice -> frag-major packed bf16, group-local wait ----
      poll16(eS2 + m * 16, p + 1);
      const float* t2p = T2 + (size_t)(m * 16 + lm) * H + wave * 32 + q * 8;
      uint4v u0, u1;
      CLOAD2(u0, u1, t2p);
      {
        float s = 0.f, ss = 0.f;
#pragma unroll
        for (int e = 0; e < 4; e++) {
          float v0 = __uint_as_float(u0[e]), v1 = __uint_as_float(u1[e]);
          s += v0 + v1; ss += v0 * v0 + v1 * v1;
        }
        s += __shfl_xor(s, 16); ss += __shfl_xor(ss, 16);
        s += __shfl_xor(s, 32); ss += __shfl_xor(ss, 32);
        if (q == 0) { red2[wave][lm] = s; red2[wave][16 + lm] = ss; }
        __syncthreads();
        float S = 0.f, SS = 0.f;
#pragma unroll
        for (int w = 0; w < 8; w++) { S += red2[w][lm]; SS += red2[w][16 + lm]; }
        float mean = S * (1.f / H);
        float var  = SS * (1.f / H) - mean * mean;
        float rsv  = rsqrtf(var + EPS);
        __syncthreads();
        int kg = wave * 32 + q * 8;
        short8 ah, al;
#pragma unroll
        for (int jj = 0; jj < 8; jj++) {
          float v = __uint_as_float((jj < 4 ? u0[jj & 3] : u1[jj & 3]));
          float a = fmaxf((v - mean) * rsv * g2s[kg + jj] + be2s[kg + jj], 0.f);
          short hi = f2bf(a);
          ah[jj] = hi;
          al[jj] = f2bf(a - bf2f(hi));
        }
        f32x4 acc = {0.f, 0.f, 0.f, 0.f};
        acc = MFMA16(ah, w3f, acc);
        acc = MFMA16(al, w3f, acc);
#pragma unroll
        for (int r = 0; r < 4; r++) red2[wave][(q * 4 + r) * 16 + lm] = acc[r];
      }
      __syncthreads();
      if (tid < 256) {
        int ri = tid >> 4, ci = tid & 15;
        float v = fb3s[ci];
#pragma unroll
        for (int w = 0; w < 8; w++) v += red2[w][tid];
        v = fmaxf(v, 0.f);
        float vo = __shfl_xor(v, 1);
        if ((ci & 1) == 0) {
          int kglob = n * 16 + ci;
          int d = (m * 9 + (kglob >> 5)) * 64 + ((kglob >> 3) & 3) * 16 + ri;
          uint u = ((uint)(unsigned short)f2bf(vo) << 16)
                 | (unsigned short)f2bf(v);
          cstoreu(t3u + d * 4 + ((kglob & 7) >> 1), u);
        }
      }
      post(eS3 + m * 16 + n, p + 1);
    }

    // ---- S4: all 256 blocks, h = blk ----
    {
      poll128(eS3, p + 1);
      {
        const uint* tb = t3u + tid * 4;
        uint4v r0, r1, r2, r3, r4, r5, r6, r7, r8;
        CLOAD9(r0, r1, r2, r3, r4, r5, r6, r7, r8,
               tb, tb + 2048, tb + 4096, tb + 6144, tb + 8192,
               tb + 10240, tb + 12288, tb + 14336, tb + 16384);
        *(uint4v*)(t3s + (size_t)(0 * 2048 + tid * 4) * 2) = r0;
        *(uint4v*)(t3s + (size_t)(1 * 2048 + tid * 4) * 2) = r1;
        *(uint4v*)(t3s + (size_t)(2 * 2048 + tid * 4) * 2) = r2;
        *(uint4v*)(t3s + (size_t)(3 * 2048 + tid * 4) * 2) = r3;
        *(uint4v*)(t3s + (size_t)(4 * 2048 + tid * 4) * 2) = r4;
        *(uint4v*)(t3s + (size_t)(5 * 2048 + tid * 4) * 2) = r5;
        *(uint4v*)(t3s + (size_t)(6 * 2048 + tid * 4) * 2) = r6;
        *(uint4v*)(t3s + (size_t)(7 * 2048 + tid * 4) * 2) = r7;
        *(uint4v*)(t3s + (size_t)(8 * 2048 + tid * 4) * 2) = r8;
      }
      __syncthreads();
      for (int mm = 0; mm < 8; mm++) {
        short8 afr[9];
#pragma unroll
        for (int kc = 0; kc < 9; kc++)
          afr[kc] = *(const short8*)(t3s + (size_t)((mm * 9 + kc) * 64 + lane) * 8);
        f32x4 acc0 = {0.f, 0.f, 0.f, 0.f}, acc1 = {0.f, 0.f, 0.f, 0.f};
#pragma unroll
        for (int kc = 0; kc < 9; kc++) {
          acc0 = MFMA16(afr[kc], bfr[0][kc], acc0);
          if (nts > 1) acc1 = MFMA16(afr[kc], bfr[1][kc], acc1);
        }
        float part[4];
#pragma unroll
        for (int r = 0; r < 4; r++) {
          int row = mm * 16 + q * 4 + r;
          float pv = acc0[r] * dX[(size_t)row * CP + nt0 * 16 + lm];
          if (nts > 1) pv += acc1[r] * dX[(size_t)row * CP + (nt0 + 1) * 16 + lm];
          part[r] = pv;
        }
#pragma unroll
        for (int r = 0; r < 4; r++) {
          part[r] += __shfl_xor(part[r], 1);
          part[r] += __shfl_xor(part[r], 2);
          part[r] += __shfl_xor(part[r], 4);
          part[r] += __shfl_xor(part[r], 8);
        }
        if (lm == 0) {
#pragma unroll
          for (int r = 0; r < 4; r++) red4[wave][mm * 16 + q * 4 + r] = part[r];
        }
      }
      __syncthreads();
      if (tid < 128) {
        int row = tid;
        float s = 0.f;
#pragma unroll
        for (int w = 0; w < 8; w++) s += red4[w][row];
        float zo = zcol[row] + scale * s;
        if (pm) zcol[row] = zo;
        if (p == NPH - 1) z[(size_t)row * H + blk] = zo;
        short hi = f2bf(zo);
        short lo = f2bf(zo - bf2f(hi));
        cstoreu(Xu + (size_t)row * H + blk,
                ((uint)(unsigned short)hi << 16) | (unsigned short)lo);
      }
      post(eS4 + blk, p + 1);
    }
  }
}

// ---------------------------------------------------------------------------
// Kernel 6: output heads
// ---------------------------------------------------------------------------
__global__ __launch_bounds__(256) void k_final(const float* __restrict__ z,
    const float* __restrict__ yW1, const float* __restrict__ yb1,
    const float* __restrict__ yW2, const float* __restrict__ yb2,
    const float* __restrict__ zW1, const float* __restrict__ zb1,
    const float* __restrict__ zW2, const float* __restrict__ zb2,
    float* __restrict__ out) {
  __shared__ float ht[H];
  __shared__ float ry[128];
  __shared__ float rz[H];
  int b = blockIdx.x, tid = threadIdx.x;
  ht[tid] = z[(size_t)b * H + tid];
  __syncthreads();
  if (tid < 128) {
    float s = yb1[tid];
    for (int k = 0; k < H; k++) s += ht[k] * yW1[k * 128 + tid];
    ry[tid] = fmaxf(s, 0.f);
  }
  {
    float s = zb1[tid];
    for (int k = 0; k < H; k++) s += ht[k] * zW1[k * H + tid];
    rz[tid] = fmaxf(s, 0.f);
  }
  __syncthreads();
  if (tid < 64) {
    float sv = ry[tid] * yW2[tid] + ry[tid + 64] * yW2[tid + 64];
    for (int off = 32; off > 0; off >>= 1) sv += __shfl_down(sv, off);
    if (tid == 0) out[b] = sv + yb2[0];
  }
  if (tid < D) {
    float s = zb2[tid];
    for (int k = 0; k < H; k++) s += rz[k] * zW2[k * D + tid];
    out[B + b * D + tid] = s;
  }
  out[B + B * D + (size_t)b * H + tid] = ht[tid];
}

// ---------------------------------------------------------------------------
extern "C" void kernel_launch(void* const* d_in, const int* in_sizes, int n_in,
                              void* d_out, int out_size, void* d_ws, size_t ws_size,
                              hipStream_t stream) {
  const float* x   = (const float*)d_in[0];
  const float* hW1 = (const float*)d_in[1];
  const float* hb1 = (const float*)d_in[2];
  const float* hW2 = (const float*)d_in[3];
  const float* hb2 = (const float*)d_in[4];
  const float* fW1 = (const float*)d_in[5];
  const float* fb1 = (const float*)d_in[6];
  const float* g1  = (const float*)d_in[7];
  const float* be1 = (const float*)d_in[8];
  const float* fW2 = (const float*)d_in[9];
  const float* fb2 = (const float*)d_in[10];
  const float* g2  = (const float*)d_in[11];
  const float* be2 = (const float*)d_in[12];
  const float* fW3 = (const float*)d_in[13];
  const float* fb3 = (const float*)d_in[14];
  const float* fW4 = (const float*)d_in[15];
  const float* fb4 = (const float*)d_in[16];
  const float* yW1 = (const float*)d_in[17];
  const float* yb1 = (const float*)d_in[18];
  const float* yW2 = (const float*)d_in[19];
  const float* yb2 = (const float*)d_in[20];
  const float* zW1 = (const float*)d_in[21];
  const float* zb1 = (const float*)d_in[22];
  const float* zW2 = (const float*)d_in[23];
  const float* zb2 = (const float*)d_in[24];
  const float* sg  = (const float*)d_in[25];
  const float* sb  = (const float*)d_in[26];

  float* ws     = (float*)d_ws;
  float* dknot  = ws;                               // 1,935,360 f
  float* dmid   = dknot + (size_t)NSEG * B * CP;    // 1,935,360 f
  float* z      = dmid + (size_t)NSEG * B * CP;     // 32,768 f
  float* T1     = z + B * H;                        // 131,072 f
  float* T2     = T1 + B * WMH;                     // 32,768 f
  uint* Xu      = (uint*)(T2 + B * H);              // 32,768 u
  uint* t3u     = Xu + B * H;                       // 18,432 u
  int* flags    = (int*)(t3u + B * KA / 2);         // 1024 i (epoch flags)
  short* w1T    = (short*)(flags + 1024);           // 262,144 s
  short* w2T    = w1T + H * WMH;                    // 262,144 s
  short* w3T    = w2T + H * WMH;                    // 65,536 s
  short* W4T    = w3T + H * H;                      // 17,694,720 s
  float* y      = (float*)W4T;                      // temp alias (dead before W4T built)

  hipLaunchKernelGGL(k_logsig, dim3(B), dim3(256), 0, stream, x, sg, sb, y);
  hipLaunchKernelGGL(k_spline, dim3(B), dim3(256), 0, stream, y, dknot, dmid);
  hipLaunchKernelGGL(k_h0,     dim3(B), dim3(256), 0, stream, x, hW1, hb1, hW2, hb2, z, Xu);
  hipLaunchKernelGGL(k_prep_t,   dim3(928, 4), dim3(256), 0, stream, fW4, W4T);
  hipLaunchKernelGGL(k_prep_pad, dim3(9728),   dim3(256), 0, stream, fb4, W4T);
  hipLaunchKernelGGL(k_prep_wt,  dim3(16, 4),  dim3(256), 0, stream, fW1, w1T, H, WMH);
  hipLaunchKernelGGL(k_prep_wt,  dim3(4, 16),  dim3(256), 0, stream, fW2, w2T, WMH, H);
  hipLaunchKernelGGL(k_prep_wt,  dim3(4, 4),   dim3(256), 0, stream, fW3, w3T, H, H);
  hipLaunchKernelGGL(k_prep_t3pad, dim3(1), dim3(128), 0, stream, (short*)t3u);
  hipLaunchKernelGGL(k_prep_zero, dim3(4), dim3(256), 0, stream, flags, 1024);

  void* args[] = {
    (void*)&w1T, (void*)&fb1, (void*)&g1, (void*)&be1,
    (void*)&w2T, (void*)&fb2, (void*)&g2, (void*)&be2,
    (void*)&w3T, (void*)&fb3, (void*)&W4T,
    (void*)&dknot, (void*)&dmid,
    (void*)&z, (void*)&Xu, (void*)&t3u,
    (void*)&T1, (void*)&T2, (void*)&flags
  };
  hipLaunchCooperativeKernel((const void*)k_scan, dim3(256), dim3(512), args, 0, stream);

  hipLaunchKernelGGL(k_final, dim3(B), dim3(256), 0, stream, z,
                     yW1, yb1, yW2, yb2, zW1, zb1, zW2, zb2, (float*)d_out);
}

// Round 6
// 3787.164 us; speedup vs baseline: 1.2786x; 1.2175x over previous
//
#include <hip/hip_runtime.h>

#define B 128
#define N 64
#define D 20
#define H 256
#define WMH 1024
#define CAUG 21
#define SIG 231
#define C 232
#define CP 240          // padded C
#define KA 288          // augmented K (256 + bias row + pad)
#define NSEG 63
#define NPH 126
#define HSTEP (1.0f/63.0f)
#define EPS 1e-5f

typedef __attribute__((ext_vector_type(8))) short short8;
typedef __attribute__((ext_vector_type(4))) float f32x4;
typedef __attribute__((ext_vector_type(4))) unsigned int uint4v;
typedef __attribute__((ext_vector_type(2))) int int2v;
typedef __attribute__((ext_vector_type(4))) int int4v;
typedef unsigned int uint;

__device__ inline short f2bf(float f) {
  uint u = __float_as_uint(f);
  uint r = (u + 0x7fffu + ((u >> 16) & 1u)) >> 16;
  return (short)r;
}
__device__ inline float bf2f(short h) {
  return __uint_as_float(((uint)(unsigned short)h) << 16);
}
#define MFMA16(a, b, c) __builtin_amdgcn_mfma_f32_16x16x32_bf16((a), (b), (c), 0, 0, 0)

// --- relaxed agent-scope scalar coherent ops (write-through to MALL)
__device__ inline void cstoreu(uint* p, uint v) {
  __hip_atomic_store(p, v, __ATOMIC_RELAXED, __HIP_MEMORY_SCOPE_AGENT);
}
__device__ inline void cstoref(float* p, float v) {
  __hip_atomic_store(p, v, __ATOMIC_RELAXED, __HIP_MEMORY_SCOPE_AGENT);
}
__device__ inline void cstorei(int* p, int v) {
  __hip_atomic_store(p, v, __ATOMIC_RELAXED, __HIP_MEMORY_SCOPE_AGENT);
}

// --- batched coherent vector loads (sc0 sc1 = read through to coherence point)
#define CLOAD8(r0,r1,r2,r3,r4,r5,r6,r7,addr)                                   \
  asm volatile("global_load_dwordx4 %0, %8, off sc0 sc1\n\t"                   \
               "global_load_dwordx4 %1, %8, off offset:16 sc0 sc1\n\t"         \
               "global_load_dwordx4 %2, %8, off offset:128 sc0 sc1\n\t"        \
               "global_load_dwordx4 %3, %8, off offset:144 sc0 sc1\n\t"        \
               "global_load_dwordx4 %4, %8, off offset:256 sc0 sc1\n\t"        \
               "global_load_dwordx4 %5, %8, off offset:272 sc0 sc1\n\t"        \
               "global_load_dwordx4 %6, %8, off offset:384 sc0 sc1\n\t"        \
               "global_load_dwordx4 %7, %8, off offset:400 sc0 sc1\n\t"        \
               "s_waitcnt vmcnt(0)"                                            \
               : "=&v"(r0), "=&v"(r1), "=&v"(r2), "=&v"(r3),                   \
                 "=&v"(r4), "=&v"(r5), "=&v"(r6), "=&v"(r7)                    \
               : "v"(addr)                                                     \
               : "memory")

#define CLOAD2(r0,r1,addr)                                                     \
  asm volatile("global_load_dwordx4 %0, %2, off sc0 sc1\n\t"                   \
               "global_load_dwordx4 %1, %2, off offset:16 sc0 sc1\n\t"         \
               "s_waitcnt vmcnt(0)"                                            \
               : "=&v"(r0), "=&v"(r1) : "v"(addr) : "memory")

// 2 independent x4 loads, one wait (S1 LDS staging)
#define CLOADB2(r0,r1,a0,a1)                                                   \
  asm volatile("global_load_dwordx4 %0, %2, off sc0 sc1\n\t"                   \
               "global_load_dwordx4 %1, %3, off sc0 sc1\n\t"                   \
               "s_waitcnt vmcnt(0)"                                            \
               : "=&v"(r0), "=&v"(r1) : "v"(a0), "v"(a1) : "memory")

// 9 x dwordx4 (full t3 stripe set) with ONE wait
#define CLOAD9(r0,r1,r2,r3,r4,r5,r6,r7,r8,a0,a1,a2,a3,a4,a5,a6,a7,a8)          \
  asm volatile("global_load_dwordx4 %0, %9, off sc0 sc1\n\t"                   \
               "global_load_dwordx4 %1, %10, off sc0 sc1\n\t"                  \
               "global_load_dwordx4 %2, %11, off sc0 sc1\n\t"                  \
               "global_load_dwordx4 %3, %12, off sc0 sc1\n\t"                  \
               "global_load_dwordx4 %4, %13, off sc0 sc1\n\t"                  \
               "global_load_dwordx4 %5, %14, off sc0 sc1\n\t"                  \
               "global_load_dwordx4 %6, %15, off sc0 sc1\n\t"                  \
               "global_load_dwordx4 %7, %16, off sc0 sc1\n\t"                  \
               "global_load_dwordx4 %8, %17, off sc0 sc1\n\t"                  \
               "s_waitcnt vmcnt(0)"                                            \
               : "=&v"(r0), "=&v"(r1), "=&v"(r2), "=&v"(r3), "=&v"(r4),        \
                 "=&v"(r5), "=&v"(r6), "=&v"(r7), "=&v"(r8)                    \
               : "v"(a0), "v"(a1), "v"(a2), "v"(a3), "v"(a4), "v"(a5),         \
                 "v"(a6), "v"(a7), "v"(a8)                                     \
               : "memory")

// ---------------------------------------------------------------------------
// Per-producer epoch flags (monotone, zeroed once at launch, NO atomics).
// ---------------------------------------------------------------------------
__device__ inline void post(int* w, int v) {
  __builtin_amdgcn_fence(__ATOMIC_RELEASE, "workgroup");   // vmcnt drain
  __syncthreads();
  if (threadIdx.x == 0) cstorei(w, v);
}
__device__ inline void poll16(const int* f, int tgt) {   // 16 producer words
  if (threadIdx.x < 64) {
    const int* p = f + (threadIdx.x & 15);
    for (;;) {
      int v;
      asm volatile("global_load_dword %0, %1, off sc0 sc1\n\ts_waitcnt vmcnt(0)"
                   : "=v"(v) : "v"(p) : "memory");
      if (__all(v >= tgt)) break;
      __builtin_amdgcn_s_sleep(1);
    }
  }
  __builtin_amdgcn_fence(__ATOMIC_ACQUIRE, "workgroup");
  __syncthreads();
}
__device__ inline void poll128(const int* f, int tgt) {  // 128 producer words
  if (threadIdx.x < 64) {
    const int* p = f + threadIdx.x * 2;
    for (;;) {
      int2v v;
      asm volatile("global_load_dwordx2 %0, %1, off sc0 sc1\n\ts_waitcnt vmcnt(0)"
                   : "=v"(v) : "v"(p) : "memory");
      if (__all(v[0] >= tgt && v[1] >= tgt)) break;
      __builtin_amdgcn_s_sleep(1);
    }
  }
  __builtin_amdgcn_fence(__ATOMIC_ACQUIRE, "workgroup");
  __syncthreads();
}
__device__ inline void poll256(const int* f, int tgt) {  // 256 producer words
  if (threadIdx.x < 64) {
    const int* p = f + threadIdx.x * 4;
    for (;;) {
      int4v v;
      asm volatile("global_load_dwordx4 %0, %1, off sc0 sc1\n\ts_waitcnt vmcnt(0)"
                   : "=v"(v) : "v"(p) : "memory");
      if (__all(v[0] >= tgt && v[1] >= tgt && v[2] >= tgt && v[3] >= tgt)) break;
      __builtin_amdgcn_s_sleep(1);
    }
  }
  __builtin_amdgcn_fence(__ATOMIC_ACQUIRE, "workgroup");
  __syncthreads();
}

__device__ inline void unpk(uint4v a, uint4v b, short8& ah, short8& al) {
#pragma unroll
  for (int e = 0; e < 4; e++) {
    ah[e]     = (short)(a[e] >> 16); al[e]     = (short)(a[e] & 0xffffu);
    ah[4 + e] = (short)(b[e] >> 16); al[4 + e] = (short)(b[e] & 0xffffu);
  }
}

// ---------------------------------------------------------------------------
// Kernel 1: depth-2 log-signature + LayerNorm -> y (B,N,C)
// ---------------------------------------------------------------------------
__global__ __launch_bounds__(256) void k_logsig(const float* __restrict__ x,
                                                const float* __restrict__ sg,
                                                const float* __restrict__ sb,
                                                float* __restrict__ y) {
  __shared__ float yb[N][C];
  int b = blockIdx.x, tid = threadIdx.x;
  for (int ii = tid; ii < N * CAUG; ii += 256) {
    int n = ii / CAUG, j = ii % CAUG;
    float v = (j == 0) ? (n * (1.0f / 63.0f)) : x[(b * N + n) * D + (j - 1)];
    yb[n][1 + j] = v;
  }
  __syncthreads();
  if (tid < 210) {
    int i = 0, rem = tid;
    while (rem >= (CAUG - 1) - i) { rem -= (CAUG - 1) - i; i++; }
    int j = i + 1 + rem;
    float acc = 0.f, pi_prev = 0.f, pj_prev = 0.f;
    for (int n = 0; n < N; n++) {
      float pi = yb[n][1 + i], pj = yb[n][1 + j];
      float di = pi - pi_prev, dj = pj - pj_prev;
      acc += 0.5f * (pi_prev * dj - di * pj_prev);
      yb[n][1 + CAUG + tid] = acc;
      pi_prev = pi; pj_prev = pj;
    }
  }
  __syncthreads();
  int w = tid >> 6, l = tid & 63;
  for (int n = w; n < N; n += 4) {
    float s1 = 0.f, s2 = 0.f;
    for (int s = l; s < SIG; s += 64) { float v = yb[n][1 + s]; s1 += v; s2 += v * v; }
    for (int off = 32; off > 0; off >>= 1) { s1 += __shfl_down(s1, off); s2 += __shfl_down(s2, off); }
    s1 = __shfl(s1, 0); s2 = __shfl(s2, 0);
    float mean = s1 * (1.0f / SIG);
    float var  = s2 * (1.0f / SIG) - mean * mean;
    float rs = rsqrtf(var + EPS);
    float* yrow = y + ((size_t)b * N + n) * C;
    if (l == 0) yrow[0] = n * (1.0f / 63.0f);
    for (int s = l; s < SIG; s += 64)
      yrow[1 + s] = (yb[n][1 + s] - mean) * rs * sg[s] + sb[s];
  }
}

// ---------------------------------------------------------------------------
// Kernel 2: natural cubic spline -> d_knot, d_mid (NSEG, B, CP) zero-padded
// ---------------------------------------------------------------------------
__global__ __launch_bounds__(256) void k_spline(const float* __restrict__ y,
                                                float* __restrict__ dknot,
                                                float* __restrict__ dmid) {
  __shared__ float yb[N * C];
  __shared__ float cp_s[62], id_s[62];
  int b = blockIdx.x, tid = threadIdx.x;
  for (int ii = tid; ii < N * C; ii += 256) yb[ii] = y[(size_t)b * N * C + ii];
  if (tid == 0) {
    const float a = HSTEP / 6.f, bb = 2.f * HSTEP / 3.f;
    float id0 = 1.f / bb; id_s[0] = id0; cp_s[0] = a * id0;
    for (int j = 1; j < 62; j++) {
      float den = bb - a * cp_s[j - 1];
      float idj = 1.f / den; id_s[j] = idj; cp_s[j] = a * idj;
    }
  }
  __syncthreads();
  int c = tid;
  if (c >= 232 && c < CP) {
    for (int n = 0; n < NSEG; n++) {
      dknot[((size_t)n * B + b) * CP + c] = 0.f;
      dmid [((size_t)n * B + b) * CP + c] = 0.f;
    }
  } else if (c < 232) {
    const float a = HSTEP / 6.f;
    float dp[62];
    dp[0] = (yb[2 * C + c] - 2.f * yb[1 * C + c] + yb[0 * C + c]) * 63.0f * id_s[0];
#pragma unroll
    for (int j = 1; j < 62; j++) {
      float rj = (yb[(j + 2) * C + c] - 2.f * yb[(j + 1) * C + c] + yb[j * C + c]) * 63.0f;
      dp[j] = (rj - a * dp[j - 1]) * id_s[j];
    }
#pragma unroll
    for (int j = 60; j >= 0; j--) dp[j] -= cp_s[j] * dp[j + 1];
#pragma unroll
    for (int n = 0; n < NSEG; n++) {
      float Mn  = (n == 0)  ? 0.f : dp[n - 1];
      float Mn1 = (n == 62) ? 0.f : dp[n];
      float dy = (yb[(n + 1) * C + c] - yb[n * C + c]) * 63.0f;
      dknot[((size_t)n * B + b) * CP + c] = dy - (HSTEP / 6.f)  * (2.f * Mn + Mn1);
      dmid [((size_t)n * B + b) * CP + c] = dy + (HSTEP / 24.f) * (Mn - Mn1);
    }
  }
}

// ---------------------------------------------------------------------------
// Kernel 3: initial hidden state -> z (f32) and Xu (packed hi|lo bf16)
// ---------------------------------------------------------------------------
__global__ __launch_bounds__(256) void k_h0(const float* __restrict__ x,
                                            const float* __restrict__ hW1,
                                            const float* __restrict__ hb1,
                                            const float* __restrict__ hW2,
                                            const float* __restrict__ hb2,
                                            float* __restrict__ z,
                                            uint* __restrict__ Xu) {
  __shared__ float r[H];
  int b = blockIdx.x, tid = threadIdx.x;
  float s = hb1[tid];
#pragma unroll
  for (int d = 0; d < D; d++) s += x[(size_t)(b * N) * D + d] * hW1[d * H + tid];
  r[tid] = fmaxf(s, 0.f);
  __syncthreads();
  float s2 = hb2[tid];
  for (int k = 0; k < H; k++) s2 += r[k] * hW2[k * H + tid];
  z[b * H + tid] = s2;
  short hi = f2bf(s2);
  short lo = f2bf(s2 - bf2f(hi));
  Xu[b * H + tid] = ((uint)(unsigned short)hi << 16) | (unsigned short)lo;
}

// ---------------------------------------------------------------------------
// Prep: transpose fW4 (256 x 59392) f32 -> W4T [h*240+c][288] bf16
// ---------------------------------------------------------------------------
__global__ __launch_bounds__(256) void k_prep_t(const float* __restrict__ fW4,
                                                short* __restrict__ W4T) {
  __shared__ float tile[64][65];
  int m0 = blockIdx.x * 64, k0 = blockIdx.y * 64;
  int lane = threadIdx.x & 63, wr = threadIdx.x >> 6;
#pragma unroll
  for (int j = 0; j < 16; j++) {
    int kk = wr * 16 + j;
    tile[kk][lane] = fW4[(size_t)(k0 + kk) * 59392 + m0 + lane];
  }
  __syncthreads();
#pragma unroll
  for (int j = 0; j < 16; j++) {
    int mloc = wr * 16 + j;
    int m = m0 + mloc;
    int hh = m / 232, cc = m - hh * 232;
    W4T[((size_t)hh * CP + cc) * KA + k0 + lane] = f2bf(tile[lane][mloc]);
  }
}

// Prep: fill k'=256 (bias), k'=257..287 zeros, and c>=232 zero rows of W4T
__global__ __launch_bounds__(256) void k_prep_pad(const float* __restrict__ fb4,
                                                  short* __restrict__ W4T) {
  int idx = blockIdx.x * 256 + threadIdx.x;
  const int partA = 61440 * 32;
  if (idx < partA) {
    int row = idx >> 5, j = idx & 31;
    int hh = row / CP, cc = row - hh * CP;
    short v = 0;
    if (j == 0 && cc < 232) v = f2bf(fb4[hh * 232 + cc]);
    W4T[(size_t)row * KA + 256 + j] = v;
  } else {
    int t = idx - partA;
    int k = t & 255; t >>= 8;
    int cc = 232 + (t & 7); int hh = t >> 3;
    W4T[((size_t)hh * CP + cc) * KA + k] = 0;
  }
}

// Prep: tiled transpose f32 (K x Nn) -> bf16 out[n][k]
__global__ __launch_bounds__(256) void k_prep_wt(const float* __restrict__ in,
                                                 short* __restrict__ out,
                                                 int K, int Nn) {
  __shared__ float tile[64][65];
  int n0 = blockIdx.x * 64, k0 = blockIdx.y * 64;
  int lane = threadIdx.x & 63, wr = threadIdx.x >> 6;
#pragma unroll
  for (int j = 0; j < 16; j++) {
    int kk = wr * 16 + j;
    tile[kk][lane] = in[(size_t)(k0 + kk) * Nn + n0 + lane];
  }
  __syncthreads();
#pragma unroll
  for (int j = 0; j < 16; j++) {
    int nl = wr * 16 + j;
    out[(size_t)(n0 + nl) * K + k0 + lane] = f2bf(tile[lane][nl]);
  }
}

// Prep: static part of frag-major t3aug (k'=256 bias=1, 257..287 = 0)
__global__ __launch_bounds__(128) void k_prep_t3pad(short* __restrict__ t3aug) {
  int r = threadIdx.x;
  if (r < 128) {
    int base = ((r >> 4) * 9 + 8) * 64 + (r & 15);
#pragma unroll
    for (int q = 0; q < 4; q++)
#pragma unroll
      for (int j = 0; j < 8; j++)
        t3aug[(size_t)(base + q * 16) * 8 + j] = (q == 0 && j == 0) ? (short)0x3F80 : (short)0;
  }
}

// Prep: zero int region
__global__ __launch_bounds__(256) void k_prep_zero(int* __restrict__ p, int n) {
  int i = blockIdx.x * 256 + threadIdx.x;
  if (i < n) p[i] = 0;
}

// ---------------------------------------------------------------------------
// Persistent scan: 256 blocks x 512 threads. Stage mapping as r4 (proven).
// De-burst changes (sync topology identical to r4):
//  - S1 stages the 16KB Xu row-slice via LDS (coalesced, 4x dedup)
//  - S2/S3 wave-rotated loads (wv=(wave+n)&7) with matching weight frags
//  - S4 t3 stripe order rotated by blk%9
//  - idle S4-only blocks prefetch next phase's dX slice into L2 (convergent)
// ---------------------------------------------------------------------------
__global__ __launch_bounds__(512, 1) void k_scan(
    const short* __restrict__ W1T, const float* __restrict__ fb1,
    const float* __restrict__ g1,  const float* __restrict__ be1,
    const short* __restrict__ W2T, const float* __restrict__ fb2,
    const float* __restrict__ g2,  const float* __restrict__ be2,
    const short* __restrict__ W3T, const float* __restrict__ fb3,
    const short* __restrict__ W4T,
    const float* __restrict__ dknot, const float* __restrict__ dmid,
    float* __restrict__ z, uint* __restrict__ Xu, uint* __restrict__ t3u,
    float* __restrict__ T1, float* __restrict__ T2,
    int* __restrict__ flags) {
  const int blk = blockIdx.x;
  const int tid = threadIdx.x;
  const int wave = tid >> 6, lane = tid & 63;
  const int lm = lane & 15, q = lane >> 4;
  const int m = (blk & 127) >> 4;   // row-group, blocks 0..127
  const int n = blk & 15;           // col-slice selector
  const int ks = wave >> 2, nwt = wave & 3;
  const int wv2 = (wave + n) & 7;   // rotated K-chunk for S2
  const int wv3 = (wave + n) & 7;   // rotated K-chunk for S3

  __shared__ short t3s[B * KA];          // 72 KB
  __shared__ float red2[8][256];         //  8 KB
  __shared__ float red4[8][128];         //  4 KB
  __shared__ float zcol[128];
  __shared__ float g1s[WMH], be1s[WMH];  //  8 KB
  __shared__ float g2s[H], be2s[H];      //  2 KB
  __shared__ float fb1s[64];
  __shared__ float fb2s[16], fb3s[16];
  __shared__ uint xs[16 * 260];          // 16.6 KB (S1 staging, padded rows)

  // per-producer epoch arrays (int each, zeroed at launch)
  int* eS1 = flags;            // [128]  (m*16+n)
  int* eS2 = flags + 128;      // [128]
  int* eS3 = flags + 256;      // [128]
  int* eS4 = flags + 384;      // [256]  (blk)

  // persistent W4 B-fragments (all blocks; h = blk)
  const int nts = (wave < 7) ? 2 : 1;
  const int nt0 = wave * 2;
  short8 bfr[2][9];
  for (int t = 0; t < nts; t++) {
    const short* wp = W4T + ((size_t)blk * CP + (nt0 + t) * 16 + lm) * KA + q * 8;
#pragma unroll
    for (int kc = 0; kc < 9; kc++)
      bfr[t][kc] = *(const short8*)(wp + kc * 32);
  }
  // persistent MLP weight fragments (blocks 0..127) — note rotated K chunks
  short8 w1f[4], w2f[4], w3f;
  if (blk < 128) {
    const short* p1 = W1T + ((size_t)(n * 64 + nwt * 16 + lm)) * H + ks * 128 + q * 8;
#pragma unroll
    for (int kc = 0; kc < 4; kc++) w1f[kc] = *(const short8*)(p1 + kc * 32);
    const short* p2 = W2T + ((size_t)(n * 16 + lm)) * WMH + wv2 * 128 + q * 8;
#pragma unroll
    for (int kc = 0; kc < 4; kc++) w2f[kc] = *(const short8*)(p2 + kc * 32);
    w3f = *(const short8*)(W3T + ((size_t)(n * 16 + lm)) * H + wv3 * 32 + q * 8);
  }
  // LDS-resident LN params and bias slices
  for (int i = tid; i < WMH; i += 512) { g1s[i] = g1[i]; be1s[i] = be1[i]; }
  for (int i = tid; i < H; i += 512)   { g2s[i] = g2[i]; be2s[i] = be2[i]; }
  if (tid < 64) fb1s[tid] = fb1[n * 64 + tid];
  if (tid < 16) { fb2s[tid] = fb2[n * 16 + tid]; fb3s[tid] = fb3[n * 16 + tid]; }
  if (tid < 128) zcol[tid] = z[(size_t)tid * H + blk];
  __syncthreads();

#pragma unroll 1
  for (int p = 0; p < NPH; p++) {
    const int seg = p >> 1, pm = p & 1;
    const float* dX = (pm ? dmid : dknot) + (size_t)seg * B * CP;
    const float scale = pm ? HSTEP : 0.5f * HSTEP;

    if (blk < 128) {
      // ---- S1: T1[m-rows, n*64 cols] = X @ W1 + fb1 ----
      if (p) poll256(eS4, p);
      {
        // stage Xu rows m*16..+15 (16KB, coalesced, each line read once)
        const uint* xsrc = Xu + (size_t)(m * 16) * H;
        int j0 = tid * 4, j1 = (tid + 512) * 4;
        uint4v v0, v1;
        CLOADB2(v0, v1, xsrc + j0, xsrc + j1);
        *(uint4v*)&xs[(j0 >> 8) * 260 + (j0 & 255)] = v0;
        *(uint4v*)&xs[(j1 >> 8) * 260 + (j1 & 255)] = v1;
      }
      __syncthreads();
      {
        f32x4 acc = {0.f, 0.f, 0.f, 0.f};
        const int xb = lm * 260 + ks * 128 + q * 8;
#pragma unroll
        for (int kc = 0; kc < 4; kc++) {
          uint4v a = *(const uint4v*)&xs[xb + kc * 32];
          uint4v b = *(const uint4v*)&xs[xb + kc * 32 + 4];
          short8 ah, al;
          unpk(a, b, ah, al);
          acc = MFMA16(ah, w1f[kc], acc);
          acc = MFMA16(al, w1f[kc], acc);
        }
#pragma unroll
        for (int r = 0; r < 4; r++) red2[wave][(q * 4 + r) * 16 + lm] = acc[r];
      }
      __syncthreads();
      if (wave < 4) {
        int col = n * 64 + wave * 16 + lm;
        float fb = fb1s[wave * 16 + lm];
#pragma unroll
        for (int r = 0; r < 4; r++) {
          int idx = (q * 4 + r) * 16 + lm;
          float v = red2[wave][idx] + red2[wave + 4][idx] + fb;
          cstoref(T1 + (size_t)(m * 16 + q * 4 + r) * WMH + col, v);
        }
      }
      post(eS1 + m * 16 + n, p + 1);

      // ---- S2: T2 slice = relu(LN1(T1)) @ W2 + fb2, group-local wait ----
      poll16(eS1 + m * 16, p + 1);
      const float* tp = T1 + (size_t)(m * 16 + lm) * WMH + wv2 * 128 + q * 8;
      uint4v yv[8];
      CLOAD8(yv[0], yv[1], yv[2], yv[3], yv[4], yv[5], yv[6], yv[7], tp);
      {
        float s = 0.f, ss = 0.f;
#pragma unroll
        for (int i = 0; i < 8; i++)
#pragma unroll
          for (int e = 0; e < 4; e++) {
            float v = __uint_as_float(yv[i][e]);
            s += v; ss += v * v;
          }
        s += __shfl_xor(s, 16); ss += __shfl_xor(ss, 16);
        s += __shfl_xor(s, 32); ss += __shfl_xor(ss, 32);
        if (q == 0) { red2[wave][lm] = s; red2[wave][16 + lm] = ss; }
        __syncthreads();
        float S = 0.f, SS = 0.f;
#pragma unroll
        for (int w = 0; w < 8; w++) { S += red2[w][lm]; SS += red2[w][16 + lm]; }
        float mean = S * (1.f / WMH);
        float var  = SS * (1.f / WMH) - mean * mean;
        float rsv  = rsqrtf(var + EPS);
        __syncthreads();
        f32x4 acc = {0.f, 0.f, 0.f, 0.f};
#pragma unroll
        for (int kc = 0; kc < 4; kc++) {
          int kg = wv2 * 128 + kc * 32 + q * 8;
          short8 ah, al;
#pragma unroll
          for (int jj = 0; jj < 8; jj++) {
            float v = __uint_as_float(yv[kc * 2 + (jj >> 2)][jj & 3]);
            float a = fmaxf((v - mean) * rsv * g1s[kg + jj] + be1s[kg + jj], 0.f);
            short hi = f2bf(a);
            ah[jj] = hi;
            al[jj] = f2bf(a - bf2f(hi));
          }
          acc = MFMA16(ah, w2f[kc], acc);
          acc = MFMA16(al, w2f[kc], acc);
        }
#pragma unroll
        for (int r = 0; r < 4; r++) red2[wave][(q * 4 + r) * 16 + lm] = acc[r];
      }
      __syncthreads();
      if (tid < 256) {
        int ri = tid >> 4, ci = tid & 15;
        float v = fb2s[ci];
#pragma unroll
        for (int w = 0; w < 8; w++) v += red2[w][tid];
        cstoref(T2 + (size_t)(m * 16 + ri) * H + n * 16 + ci, v);
      }
      post(eS2 + m * 16 + n, p + 1);

      // ---- S3: t3 slice -> frag-major packed bf16, group-local wait ----
      poll16(eS2 + m * 16, p + 1);
      const float* t2p = T2 + (size_t)(m * 16 + lm) * H + wv3 * 32 + q * 8;
      uint4v u0, u1;
      CLOAD2(u0, u1, t2p);
      {
        float s = 0.f, ss = 0.f;
#pragma unroll
        for (int e = 0; e < 4; e++) {
          float v0 = __uint_as_float(u0[e]), v1 = __uint_as_float(u1[e]);
          s += v0 + v1; ss += v0 * v0 + v1 * v1;
        }
        s += __shfl_xor(s, 16); ss += __shfl_xor(ss, 16);
        s += __shfl_xor(s, 32); ss += __shfl_xor(ss, 32);
        if (q == 0) { red2[wave][lm] = s; red2[wave][16 + lm] = ss; }
        __syncthreads();
        float S = 0.f, SS = 0.f;
#pragma unroll
        for (int w = 0; w < 8; w++) { S += red2[w][lm]; SS += red2[w][16 + lm]; }
        float mean = S * (1.f / H);
        float var  = SS * (1.f / H) - mean * mean;
        float rsv  = rsqrtf(var + EPS);
        __syncthreads();
        int kg = wv3 * 32 + q * 8;
        short8 ah, al;
#pragma unroll
        for (int jj = 0; jj < 8; jj++) {
          float v = __uint_as_float((jj < 4 ? u0[jj & 3] : u1[jj & 3]));
          float a = fmaxf((v - mean) * rsv * g2s[kg + jj] + be2s[kg + jj], 0.f);
          short hi = f2bf(a);
          ah[jj] = hi;
          al[jj] = f2bf(a - bf2f(hi));
        }
        f32x4 acc = {0.f, 0.f, 0.f, 0.f};
        acc = MFMA16(ah, w3f, acc);
        acc = MFMA16(al, w3f, acc);
#pragma unroll
        for (int r = 0; r < 4; r++) red2[wave][(q * 4 + r) * 16 + lm] = acc[r];
      }
      __syncthreads();
      if (tid < 256) {
        int ri = tid >> 4, ci = tid & 15;
        float v = fb3s[ci];
#pragma unroll
        for (int w = 0; w < 8; w++) v += red2[w][tid];
        v = fmaxf(v, 0.f);
        float vo = __shfl_xor(v, 1);
        if ((ci & 1) == 0) {
          int kglob = n * 16 + ci;
          int d = (m * 9 + (kglob >> 5)) * 64 + ((kglob >> 3) & 3) * 16 + ri;
          uint u = ((uint)(unsigned short)f2bf(vo) << 16)
                 | (unsigned short)f2bf(v);
          cstoreu(t3u + d * 4 + ((kglob & 7) >> 1), u);
        }
      }
      post(eS3 + m * 16 + n, p + 1);
    } else {
      // idle S4-only block: prefetch next phase's dX slice into this XCD's L2
      // (convergent: all lanes execute, indices clamped)
      if (p + 1 < NPH) {
        const int seg2 = (p + 1) >> 1, pm2 = (p + 1) & 1;
        const float* dX2 = (pm2 ? dmid : dknot) + (size_t)seg2 * B * CP;
        int i0 = tid * 64;
        if (i0 > B * CP - 64) i0 = B * CP - 64;
        int i1 = i0 + 32;
        float t0, t1;
        asm volatile("global_load_dword %0, %2, off\n\t"
                     "global_load_dword %1, %3, off\n\t"
                     "s_waitcnt vmcnt(0)"
                     : "=&v"(t0), "=&v"(t1)
                     : "v"(dX2 + i0), "v"(dX2 + i1) : "memory");
        asm volatile("" :: "v"(t0), "v"(t1));
      }
    }

    // ---- S4: all 256 blocks, h = blk ----
    {
      poll128(eS3, p + 1);
      {
        // stripe-rotated t3 broadcast load (de-synchronized across blocks)
        int s0 = blk % 9;
        int s1 = s0 + 1 >= 9 ? s0 + 1 - 9 : s0 + 1;
        int s2 = s1 + 1 >= 9 ? s1 + 1 - 9 : s1 + 1;
        int s3 = s2 + 1 >= 9 ? s2 + 1 - 9 : s2 + 1;
        int s4 = s3 + 1 >= 9 ? s3 + 1 - 9 : s3 + 1;
        int s5 = s4 + 1 >= 9 ? s4 + 1 - 9 : s4 + 1;
        int s6 = s5 + 1 >= 9 ? s5 + 1 - 9 : s5 + 1;
        int s7 = s6 + 1 >= 9 ? s6 + 1 - 9 : s6 + 1;
        int s8 = s7 + 1 >= 9 ? s7 + 1 - 9 : s7 + 1;
        const uint* tb = t3u + tid * 4;
        uint4v r0, r1, r2, r3, r4, r5, r6, r7, r8;
        CLOAD9(r0, r1, r2, r3, r4, r5, r6, r7, r8,
               tb + s0 * 2048, tb + s1 * 2048, tb + s2 * 2048,
               tb + s3 * 2048, tb + s4 * 2048, tb + s5 * 2048,
               tb + s6 * 2048, tb + s7 * 2048, tb + s8 * 2048);
        *(uint4v*)(t3s + (size_t)s0 * 4096 + tid * 8) = r0;
        *(uint4v*)(t3s + (size_t)s1 * 4096 + tid * 8) = r1;
        *(uint4v*)(t3s + (size_t)s2 * 4096 + tid * 8) = r2;
        *(uint4v*)(t3s + (size_t)s3 * 4096 + tid * 8) = r3;
        *(uint4v*)(t3s + (size_t)s4 * 4096 + tid * 8) = r4;
        *(uint4v*)(t3s + (size_t)s5 * 4096 + tid * 8) = r5;
        *(uint4v*)(t3s + (size_t)s6 * 4096 + tid * 8) = r6;
        *(uint4v*)(t3s + (size_t)s7 * 4096 + tid * 8) = r7;
        *(uint4v*)(t3s + (size_t)s8 * 4096 + tid * 8) = r8;
      }
      __syncthreads();
      for (int mm = 0; mm < 8; mm++) {
        short8 afr[9];
#pragma unroll
        for (int kc = 0; kc < 9; kc++)
          afr[kc] = *(const short8*)(t3s + (size_t)((mm * 9 + kc) * 64 + lane) * 8);
        f32x4 acc0 = {0.f, 0.f, 0.f, 0.f}, acc1 = {0.f, 0.f, 0.f, 0.f};
#pragma unroll
        for (int kc = 0; kc < 9; kc++) {
          acc0 = MFMA16(afr[kc], bfr[0][kc], acc0);
          if (nts > 1) acc1 = MFMA16(afr[kc], bfr[1][kc], acc1);
        }
        float part[4];
#pragma unroll
        for (int r = 0; r < 4; r++) {
          int row = mm * 16 + q * 4 + r;
          float pv = acc0[r] * dX[(size_t)row * CP + nt0 * 16 + lm];
          if (nts > 1) pv += acc1[r] * dX[(size_t)row * CP + (nt0 + 1) * 16 + lm];
          part[r] = pv;
        }
#pragma unroll
        for (int r = 0; r < 4; r++) {
          part[r] += __shfl_xor(part[r], 1);
          part[r] += __shfl_xor(part[r], 2);
          part[r] += __shfl_xor(part[r], 4);
          part[r] += __shfl_xor(part[r], 8);
        }
        if (lm == 0) {
#pragma unroll
          for (int r = 0; r < 4; r++) red4[wave][mm * 16 + q * 4 + r] = part[r];
        }
      }
      __syncthreads();
      if (tid < 128) {
        int row = tid;
        float s = 0.f;
#pragma unroll
        for (int w = 0; w < 8; w++) s += red4[w][row];
        float zo = zcol[row] + scale * s;
        if (pm) zcol[row] = zo;
        if (p == NPH - 1) z[(size_t)row * H + blk] = zo;
        short hi = f2bf(zo);
        short lo = f2bf(zo - bf2f(hi));
        cstoreu(Xu + (size_t)row * H + blk,
                ((uint)(unsigned short)hi << 16) | (unsigned short)lo);
      }
      post(eS4 + blk, p + 1);
    }
  }
}

// ---------------------------------------------------------------------------
// Kernel 6: output heads
// ---------------------------------------------------------------------------
__global__ __launch_bounds__(256) void k_final(const float* __restrict__ z,
    const float* __restrict__ yW1, const float* __restrict__ yb1,
    const float* __restrict__ yW2, const float* __restrict__ yb2,
    const float* __restrict__ zW1, const float* __restrict__ zb1,
    const float* __restrict__ zW2, const float* __restrict__ zb2,
    float* __restrict__ out) {
  __shared__ float ht[H];
  __shared__ float ry[128];
  __shared__ float rz[H];
  int b = blockIdx.x, tid = threadIdx.x;
  ht[tid] = z[(size_t)b * H + tid];
  __syncthreads();
  if (tid < 128) {
    float s = yb1[tid];
    for (int k = 0; k < H; k++) s += ht[k] * yW1[k * 128 + tid];
    ry[tid] = fmaxf(s, 0.f);
  }
  {
    float s = zb1[tid];
    for (int k = 0; k < H; k++) s += ht[k] * zW1[k * H + tid];
    rz[tid] = fmaxf(s, 0.f);
  }
  __syncthreads();
  if (tid < 64) {
    float sv = ry[tid] * yW2[tid] + ry[tid + 64] * yW2[tid + 64];
    for (int off = 32; off > 0; off >>= 1) sv += __shfl_down(sv, off);
    if (tid == 0) out[b] = sv + yb2[0];
  }
  if (tid < D) {
    float s = zb2[tid];
    for (int k = 0; k < H; k++) s += rz[k] * zW2[k * D + tid];
    out[B + b * D + tid] = s;
  }
  out[B + B * D + (size_t)b * H + tid] = ht[tid];
}

// ---------------------------------------------------------------------------
extern "C" void kernel_launch(void* const* d_in, const int* in_sizes, int n_in,
                              void* d_out, int out_size, void* d_ws, size_t ws_size,
                              hipStream_t stream) {
  const float* x   = (const float*)d_in[0];
  const float* hW1 = (const float*)d_in[1];
  const float* hb1 = (const float*)d_in[2];
  const float* hW2 = (const float*)d_in[3];
  const float* hb2 = (const float*)d_in[4];
  const float* fW1 = (const float*)d_in[5];
  const float* fb1 = (const float*)d_in[6];
  const float* g1  = (const float*)d_in[7];
  const float* be1 = (const float*)d_in[8];
  const float* fW2 = (const float*)d_in[9];
  const float* fb2 = (const float*)d_in[10];
  const float* g2  = (const float*)d_in[11];
  const float* be2 = (const float*)d_in[12];
  const float* fW3 = (const float*)d_in[13];
  const float* fb3 = (const float*)d_in[14];
  const float* fW4 = (const float*)d_in[15];
  const float* fb4 = (const float*)d_in[16];
  const float* yW1 = (const float*)d_in[17];
  const float* yb1 = (const float*)d_in[18];
  const float* yW2 = (const float*)d_in[19];
  const float* yb2 = (const float*)d_in[20];
  const float* zW1 = (const float*)d_in[21];
  const float* zb1 = (const float*)d_in[22];
  const float* zW2 = (const float*)d_in[23];
  const float* zb2 = (const float*)d_in[24];
  const float* sg  = (const float*)d_in[25];
  const float* sb  = (const float*)d_in[26];

  float* ws     = (float*)d_ws;
  float* dknot  = ws;                               // 1,935,360 f
  float* dmid   = dknot + (size_t)NSEG * B * CP;    // 1,935,360 f
  float* z      = dmid + (size_t)NSEG * B * CP;     // 32,768 f
  float* T1     = z + B * H;                        // 131,072 f
  float* T2     = T1 + B * WMH;                     // 32,768 f
  uint* Xu      = (uint*)(T2 + B * H);              // 32,768 u
  uint* t3u     = Xu + B * H;                       // 18,432 u
  int* flags    = (int*)(t3u + B * KA / 2);         // 1024 i (epoch flags)
  short* w1T    = (short*)(flags + 1024);           // 262,144 s
  short* w2T    = w1T + H * WMH;                    // 262,144 s
  short* w3T    = w2T + H * WMH;                    // 65,536 s
  short* W4T    = w3T + H * H;                      // 17,694,720 s
  float* y      = (float*)W4T;                      // temp alias (dead before W4T built)

  hipLaunchKernelGGL(k_logsig, dim3(B), dim3(256), 0, stream, x, sg, sb, y);
  hipLaunchKernelGGL(k_spline, dim3(B), dim3(256), 0, stream, y, dknot, dmid);
  hipLaunchKernelGGL(k_h0,     dim3(B), dim3(256), 0, stream, x, hW1, hb1, hW2, hb2, z, Xu);
  hipLaunchKernelGGL(k_prep_t,   dim3(928, 4), dim3(256), 0, stream, fW4, W4T);
  hipLaunchKernelGGL(k_prep_pad, dim3(9728),   dim3(256), 0, stream, fb4, W4T);
  hipLaunchKernelGGL(k_prep_wt,  dim3(16, 4),  dim3(256), 0, stream, fW1, w1T, H, WMH);
  hipLaunchKernelGGL(k_prep_wt,  dim3(4, 16),  dim3(256), 0, stream, fW2, w2T, WMH, H);
  hipLaunchKernelGGL(k_prep_wt,  dim3(4, 4),   dim3(256), 0, stream, fW3, w3T, H, H);
  hipLaunchKernelGGL(k_prep_t3pad, dim3(1), dim3(128), 0, stream, (short*)t3u);
  hipLaunchKernelGGL(k_prep_zero, dim3(4), dim3(256), 0, stream, flags, 1024);

  void* args[] = {
    (void*)&w1T, (void*)&fb1, (void*)&g1, (void*)&be1,
    (void*)&w2T, (void*)&fb2, (void*)&g2, (void*)&be2,
    (void*)&w3T, (void*)&fb3, (void*)&W4T,
    (void*)&dknot, (void*)&dmid,
    (void*)&z, (void*)&Xu, (void*)&t3u,
    (void*)&T1, (void*)&T2, (void*)&flags
  };
  hipLaunchCooperativeKernel((const void*)k_scan, dim3(256), dim3(512), args, 0, stream);

  hipLaunchKernelGGL(k_final, dim3(B), dim3(256), 0, stream, z,
                     yW1, yb1, yW2, yb2, zW1, zb1, zW2, zb2, (float*)d_out);
}

// Round 7
// 3696.568 us; speedup vs baseline: 1.3099x; 1.0245x over previous
//
#include <hip/hip_runtime.h>

#define B 128
#define N 64
#define D 20
#define H 256
#define WMH 1024
#define CAUG 21
#define SIG 231
#define C 232
#define CP 240          // padded C
#define KA 288          // augmented K (256 + bias row + pad)
#define NSEG 63
#define NPH 126
#define HSTEP (1.0f/63.0f)
#define EPS 1e-5f

typedef __attribute__((ext_vector_type(8))) short short8;
typedef __attribute__((ext_vector_type(4))) float f32x4;
typedef __attribute__((ext_vector_type(4))) unsigned int uint4v;
typedef __attribute__((ext_vector_type(2))) int int2v;
typedef __attribute__((ext_vector_type(4))) int int4v;
typedef unsigned int uint;

__device__ inline short f2bf(float f) {
  uint u = __float_as_uint(f);
  uint r = (u + 0x7fffu + ((u >> 16) & 1u)) >> 16;
  return (short)r;
}
__device__ inline float bf2f(short h) {
  return __uint_as_float(((uint)(unsigned short)h) << 16);
}
#define MFMA16(a, b, c) __builtin_amdgcn_mfma_f32_16x16x32_bf16((a), (b), (c), 0, 0, 0)

// --- relaxed agent-scope scalar coherent ops (write-through to MALL)
__device__ inline void cstoreu(uint* p, uint v) {
  __hip_atomic_store(p, v, __ATOMIC_RELAXED, __HIP_MEMORY_SCOPE_AGENT);
}
__device__ inline void cstoref(float* p, float v) {
  __hip_atomic_store(p, v, __ATOMIC_RELAXED, __HIP_MEMORY_SCOPE_AGENT);
}
__device__ inline void cstorei(int* p, int v) {
  __hip_atomic_store(p, v, __ATOMIC_RELAXED, __HIP_MEMORY_SCOPE_AGENT);
}
__device__ inline void catomadd(float* p, float v) {
  (void)__hip_atomic_fetch_add(p, v, __ATOMIC_RELAXED, __HIP_MEMORY_SCOPE_AGENT);
}
__device__ inline float cloadf(const float* p) {
  float v;
  asm volatile("global_load_dword %0, %1, off sc0 sc1\n\ts_waitcnt vmcnt(0)"
               : "=v"(v) : "v"(p) : "memory");
  return v;
}

// --- batched coherent vector loads (sc0 sc1 = read through to coherence point)
#define CLOAD2(r0,r1,addr)                                                     \
  asm volatile("global_load_dwordx4 %0, %2, off sc0 sc1\n\t"                   \
               "global_load_dwordx4 %1, %2, off offset:16 sc0 sc1\n\t"         \
               "s_waitcnt vmcnt(0)"                                            \
               : "=&v"(r0), "=&v"(r1) : "v"(addr) : "memory")

// 2 independent x4 loads, one wait (S1 LDS staging)
#define CLOADB2(r0,r1,a0,a1)                                                   \
  asm volatile("global_load_dwordx4 %0, %2, off sc0 sc1\n\t"                   \
               "global_load_dwordx4 %1, %3, off sc0 sc1\n\t"                   \
               "s_waitcnt vmcnt(0)"                                            \
               : "=&v"(r0), "=&v"(r1) : "v"(a0), "v"(a1) : "memory")

// 9 x dwordx4 (full t3 stripe set) with ONE wait
#define CLOAD9(r0,r1,r2,r3,r4,r5,r6,r7,r8,a0,a1,a2,a3,a4,a5,a6,a7,a8)          \
  asm volatile("global_load_dwordx4 %0, %9, off sc0 sc1\n\t"                   \
               "global_load_dwordx4 %1, %10, off sc0 sc1\n\t"                  \
               "global_load_dwordx4 %2, %11, off sc0 sc1\n\t"                  \
               "global_load_dwordx4 %3, %12, off sc0 sc1\n\t"                  \
               "global_load_dwordx4 %4, %13, off sc0 sc1\n\t"                  \
               "global_load_dwordx4 %5, %14, off sc0 sc1\n\t"                  \
               "global_load_dwordx4 %6, %15, off sc0 sc1\n\t"                  \
               "global_load_dwordx4 %7, %16, off sc0 sc1\n\t"                  \
               "global_load_dwordx4 %8, %17, off sc0 sc1\n\t"                  \
               "s_waitcnt vmcnt(0)"                                            \
               : "=&v"(r0), "=&v"(r1), "=&v"(r2), "=&v"(r3), "=&v"(r4),        \
                 "=&v"(r5), "=&v"(r6), "=&v"(r7), "=&v"(r8)                    \
               : "v"(a0), "v"(a1), "v"(a2), "v"(a3), "v"(a4), "v"(a5),         \
                 "v"(a6), "v"(a7), "v"(a8)                                     \
               : "memory")

// ---------------------------------------------------------------------------
// Per-producer epoch flags (monotone, zeroed once at launch, NO atomics).
// ---------------------------------------------------------------------------
__device__ inline void post(int* w, int v) {
  __builtin_amdgcn_fence(__ATOMIC_RELEASE, "workgroup");   // vmcnt drain
  __syncthreads();
  if (threadIdx.x == 0) cstorei(w, v);
}
__device__ inline void poll16(const int* f, int tgt) {   // 16 producer words
  if (threadIdx.x < 64) {
    const int* p = f + (threadIdx.x & 15);
    for (;;) {
      int v;
      asm volatile("global_load_dword %0, %1, off sc0 sc1\n\ts_waitcnt vmcnt(0)"
                   : "=v"(v) : "v"(p) : "memory");
      if (__all(v >= tgt)) break;
      __builtin_amdgcn_s_sleep(1);
    }
  }
  __builtin_amdgcn_fence(__ATOMIC_ACQUIRE, "workgroup");
  __syncthreads();
}
__device__ inline void poll128(const int* f, int tgt) {  // 128 producer words
  if (threadIdx.x < 64) {
    const int* p = f + threadIdx.x * 2;
    for (;;) {
      int2v v;
      asm volatile("global_load_dwordx2 %0, %1, off sc0 sc1\n\ts_waitcnt vmcnt(0)"
                   : "=v"(v) : "v"(p) : "memory");
      if (__all(v[0] >= tgt && v[1] >= tgt)) break;
      __builtin_amdgcn_s_sleep(1);
    }
  }
  __builtin_amdgcn_fence(__ATOMIC_ACQUIRE, "workgroup");
  __syncthreads();
}
__device__ inline void poll256(const int* f, int tgt) {  // 256 producer words
  if (threadIdx.x < 64) {
    const int* p = f + threadIdx.x * 4;
    for (;;) {
      int4v v;
      asm volatile("global_load_dwordx4 %0, %1, off sc0 sc1\n\ts_waitcnt vmcnt(0)"
                   : "=v"(v) : "v"(p) : "memory");
      if (__all(v[0] >= tgt && v[1] >= tgt && v[2] >= tgt && v[3] >= tgt)) break;
      __builtin_amdgcn_s_sleep(1);
    }
  }
  __builtin_amdgcn_fence(__ATOMIC_ACQUIRE, "workgroup");
  __syncthreads();
}

__device__ inline void unpk(uint4v a, uint4v b, short8& ah, short8& al) {
#pragma unroll
  for (int e = 0; e < 4; e++) {
    ah[e]     = (short)(a[e] >> 16); al[e]     = (short)(a[e] & 0xffffu);
    ah[4 + e] = (short)(b[e] >> 16); al[4 + e] = (short)(b[e] & 0xffffu);
  }
}

// ---------------------------------------------------------------------------
// Kernel 1: depth-2 log-signature + LayerNorm -> y (B,N,C)
// ---------------------------------------------------------------------------
__global__ __launch_bounds__(256) void k_logsig(const float* __restrict__ x,
                                                const float* __restrict__ sg,
                                                const float* __restrict__ sb,
                                                float* __restrict__ y) {
  __shared__ float yb[N][C];
  int b = blockIdx.x, tid = threadIdx.x;
  for (int ii = tid; ii < N * CAUG; ii += 256) {
    int n = ii / CAUG, j = ii % CAUG;
    float v = (j == 0) ? (n * (1.0f / 63.0f)) : x[(b * N + n) * D + (j - 1)];
    yb[n][1 + j] = v;
  }
  __syncthreads();
  if (tid < 210) {
    int i = 0, rem = tid;
    while (rem >= (CAUG - 1) - i) { rem -= (CAUG - 1) - i; i++; }
    int j = i + 1 + rem;
    float acc = 0.f, pi_prev = 0.f, pj_prev = 0.f;
    for (int n = 0; n < N; n++) {
      float pi = yb[n][1 + i], pj = yb[n][1 + j];
      float di = pi - pi_prev, dj = pj - pj_prev;
      acc += 0.5f * (pi_prev * dj - di * pj_prev);
      yb[n][1 + CAUG + tid] = acc;
      pi_prev = pi; pj_prev = pj;
    }
  }
  __syncthreads();
  int w = tid >> 6, l = tid & 63;
  for (int n = w; n < N; n += 4) {
    float s1 = 0.f, s2 = 0.f;
    for (int s = l; s < SIG; s += 64) { float v = yb[n][1 + s]; s1 += v; s2 += v * v; }
    for (int off = 32; off > 0; off >>= 1) { s1 += __shfl_down(s1, off); s2 += __shfl_down(s2, off); }
    s1 = __shfl(s1, 0); s2 = __shfl(s2, 0);
    float mean = s1 * (1.0f / SIG);
    float var  = s2 * (1.0f / SIG) - mean * mean;
    float rs = rsqrtf(var + EPS);
    float* yrow = y + ((size_t)b * N + n) * C;
    if (l == 0) yrow[0] = n * (1.0f / 63.0f);
    for (int s = l; s < SIG; s += 64)
      yrow[1 + s] = (yb[n][1 + s] - mean) * rs * sg[s] + sb[s];
  }
}

// ---------------------------------------------------------------------------
// Kernel 2: natural cubic spline -> d_knot, d_mid (NSEG, B, CP) zero-padded
// ---------------------------------------------------------------------------
__global__ __launch_bounds__(256) void k_spline(const float* __restrict__ y,
                                                float* __restrict__ dknot,
                                                float* __restrict__ dmid) {
  __shared__ float yb[N * C];
  __shared__ float cp_s[62], id_s[62];
  int b = blockIdx.x, tid = threadIdx.x;
  for (int ii = tid; ii < N * C; ii += 256) yb[ii] = y[(size_t)b * N * C + ii];
  if (tid == 0) {
    const float a = HSTEP / 6.f, bb = 2.f * HSTEP / 3.f;
    float id0 = 1.f / bb; id_s[0] = id0; cp_s[0] = a * id0;
    for (int j = 1; j < 62; j++) {
      float den = bb - a * cp_s[j - 1];
      float idj = 1.f / den; id_s[j] = idj; cp_s[j] = a * idj;
    }
  }
  __syncthreads();
  int c = tid;
  if (c >= 232 && c < CP) {
    for (int n = 0; n < NSEG; n++) {
      dknot[((size_t)n * B + b) * CP + c] = 0.f;
      dmid [((size_t)n * B + b) * CP + c] = 0.f;
    }
  } else if (c < 232) {
    const float a = HSTEP / 6.f;
    float dp[62];
    dp[0] = (yb[2 * C + c] - 2.f * yb[1 * C + c] + yb[0 * C + c]) * 63.0f * id_s[0];
#pragma unroll
    for (int j = 1; j < 62; j++) {
      float rj = (yb[(j + 2) * C + c] - 2.f * yb[(j + 1) * C + c] + yb[j * C + c]) * 63.0f;
      dp[j] = (rj - a * dp[j - 1]) * id_s[j];
    }
#pragma unroll
    for (int j = 60; j >= 0; j--) dp[j] -= cp_s[j] * dp[j + 1];
#pragma unroll
    for (int n = 0; n < NSEG; n++) {
      float Mn  = (n == 0)  ? 0.f : dp[n - 1];
      float Mn1 = (n == 62) ? 0.f : dp[n];
      float dy = (yb[(n + 1) * C + c] - yb[n * C + c]) * 63.0f;
      dknot[((size_t)n * B + b) * CP + c] = dy - (HSTEP / 6.f)  * (2.f * Mn + Mn1);
      dmid [((size_t)n * B + b) * CP + c] = dy + (HSTEP / 24.f) * (Mn - Mn1);
    }
  }
}

// ---------------------------------------------------------------------------
// Kernel 3: initial hidden state -> z (f32) and Xu (packed hi|lo bf16)
// ---------------------------------------------------------------------------
__global__ __launch_bounds__(256) void k_h0(const float* __restrict__ x,
                                            const float* __restrict__ hW1,
                                            const float* __restrict__ hb1,
                                            const float* __restrict__ hW2,
                                            const float* __restrict__ hb2,
                                            float* __restrict__ z,
                                            uint* __restrict__ Xu) {
  __shared__ float r[H];
  int b = blockIdx.x, tid = threadIdx.x;
  float s = hb1[tid];
#pragma unroll
  for (int d = 0; d < D; d++) s += x[(size_t)(b * N) * D + d] * hW1[d * H + tid];
  r[tid] = fmaxf(s, 0.f);
  __syncthreads();
  float s2 = hb2[tid];
  for (int k = 0; k < H; k++) s2 += r[k] * hW2[k * H + tid];
  z[b * H + tid] = s2;
  short hi = f2bf(s2);
  short lo = f2bf(s2 - bf2f(hi));
  Xu[b * H + tid] = ((uint)(unsigned short)hi << 16) | (unsigned short)lo;
}

// ---------------------------------------------------------------------------
// Prep: transpose fW4 (256 x 59392) f32 -> W4T [h*240+c][288] bf16
// ---------------------------------------------------------------------------
__global__ __launch_bounds__(256) void k_prep_t(const float* __restrict__ fW4,
                                                short* __restrict__ W4T) {
  __shared__ float tile[64][65];
  int m0 = blockIdx.x * 64, k0 = blockIdx.y * 64;
  int lane = threadIdx.x & 63, wr = threadIdx.x >> 6;
#pragma unroll
  for (int j = 0; j < 16; j++) {
    int kk = wr * 16 + j;
    tile[kk][lane] = fW4[(size_t)(k0 + kk) * 59392 + m0 + lane];
  }
  __syncthreads();
#pragma unroll
  for (int j = 0; j < 16; j++) {
    int mloc = wr * 16 + j;
    int m = m0 + mloc;
    int hh = m / 232, cc = m - hh * 232;
    W4T[((size_t)hh * CP + cc) * KA + k0 + lane] = f2bf(tile[lane][mloc]);
  }
}

// Prep: fill k'=256 (bias), k'=257..287 zeros, and c>=232 zero rows of W4T
__global__ __launch_bounds__(256) void k_prep_pad(const float* __restrict__ fb4,
                                                  short* __restrict__ W4T) {
  int idx = blockIdx.x * 256 + threadIdx.x;
  const int partA = 61440 * 32;
  if (idx < partA) {
    int row = idx >> 5, j = idx & 31;
    int hh = row / CP, cc = row - hh * CP;
    short v = 0;
    if (j == 0 && cc < 232) v = f2bf(fb4[hh * 232 + cc]);
    W4T[(size_t)row * KA + 256 + j] = v;
  } else {
    int t = idx - partA;
    int k = t & 255; t >>= 8;
    int cc = 232 + (t & 7); int hh = t >> 3;
    W4T[((size_t)hh * CP + cc) * KA + k] = 0;
  }
}

// Prep: tiled transpose f32 (K x Nn) -> bf16 out[n][k]
__global__ __launch_bounds__(256) void k_prep_wt(const float* __restrict__ in,
                                                 short* __restrict__ out,
                                                 int K, int Nn) {
  __shared__ float tile[64][65];
  int n0 = blockIdx.x * 64, k0 = blockIdx.y * 64;
  int lane = threadIdx.x & 63, wr = threadIdx.x >> 6;
#pragma unroll
  for (int j = 0; j < 16; j++) {
    int kk = wr * 16 + j;
    tile[kk][lane] = in[(size_t)(k0 + kk) * Nn + n0 + lane];
  }
  __syncthreads();
#pragma unroll
  for (int j = 0; j < 16; j++) {
    int nl = wr * 16 + j;
    out[(size_t)(n0 + nl) * K + k0 + lane] = f2bf(tile[lane][nl]);
  }
}

// Prep: static part of frag-major t3aug (k'=256 bias=1, 257..287 = 0)
__global__ __launch_bounds__(128) void k_prep_t3pad(short* __restrict__ t3aug) {
  int r = threadIdx.x;
  if (r < 128) {
    int base = ((r >> 4) * 9 + 8) * 64 + (r & 15);
#pragma unroll
    for (int q = 0; q < 4; q++)
#pragma unroll
      for (int j = 0; j < 8; j++)
        t3aug[(size_t)(base + q * 16) * 8 + j] = (q == 0 && j == 0) ? (short)0x3F80 : (short)0;
  }
}

// Prep: zero int region
__global__ __launch_bounds__(256) void k_prep_zero(int* __restrict__ p, int n) {
  int i = blockIdx.x * 256 + threadIdx.x;
  if (i < n) p[i] = 0;
}

// ---------------------------------------------------------------------------
// Persistent scan: 256 blocks x 512 threads. Per phase:
// S12 (blk<128, (m,n)): X@W1 slice -> t1s LDS; stats hop (32 f per block);
//       relu(LN1(t1s)) @ W2[n's 64 K-rows, all 256 cols] partial-K ->
//       f32-atomic-add into parity buffer T2cur. T1 buffer DELETED.
// S3  (blk<128): LN2(T2cur) @ W3 slice -> frag-major packed bf16 t3
// S4  (all 256, h=blk): z += scale*(t3 @ W4[h]).dX; MLP blocks zero the
//       consumed T2 parity buffer (safe: after poll128(eS3) all reads done).
// Sync: per-producer epoch flags + wave-parallel wide polls (r6 skeleton).
// ---------------------------------------------------------------------------
__global__ __launch_bounds__(512, 1) void k_scan(
    const short* __restrict__ W1T, const float* __restrict__ fb1,
    const float* __restrict__ g1,  const float* __restrict__ be1,
    const short* __restrict__ W2T, const float* __restrict__ fb2,
    const float* __restrict__ g2,  const float* __restrict__ be2,
    const short* __restrict__ W3T, const float* __restrict__ fb3,
    const short* __restrict__ W4T,
    const float* __restrict__ dknot, const float* __restrict__ dmid,
    float* __restrict__ z, uint* __restrict__ Xu, uint* __restrict__ t3u,
    float* __restrict__ T2d, float* __restrict__ statsG,
    int* __restrict__ flags) {
  const int blk = blockIdx.x;
  const int tid = threadIdx.x;
  const int wave = tid >> 6, lane = tid & 63;
  const int lm = lane & 15, q = lane >> 4;
  const int m = (blk & 127) >> 4;   // row-group, blocks 0..127
  const int n = blk & 15;           // col-slice selector
  const int ks = wave >> 2, nwt = wave & 3;
  const int wv3 = (wave + n) & 7;   // rotated K-chunk for S3

  __shared__ short t3s[B * KA];          // 72 KB
  __shared__ float red2[8][256];         //  8 KB (reduce + stats staging)
  __shared__ float red4[8][128];         //  4 KB
  __shared__ float zcol[128];
  __shared__ float g1s[WMH], be1s[WMH];  //  8 KB
  __shared__ float g2s[H], be2s[H];      //  2 KB
  __shared__ float fb1s[64];
  __shared__ float fb2F[H];              //  1 KB (full fb2)
  __shared__ float fb3s[16];
  __shared__ uint xs[16 * 260];          // 16.6 KB (S1 staging, padded rows)
  __shared__ float t1s[16][68];          //  4.3 KB (T1 slice, LDS-resident)
  __shared__ float fstat[32];            // full LN1 stats (row*2+{s,ss})

  // per-producer epoch arrays (int each, zeroed at launch)
  int* eS1 = flags;            // [128]  (m*16+n)  stats ready
  int* eS2 = flags + 128;      // [128]            T2 partial added
  int* eS3 = flags + 256;      // [128]            t3 ready
  int* eS4 = flags + 384;      // [256]  (blk)     X ready

  // persistent W4 B-fragments (all blocks; h = blk)
  const int nts = (wave < 7) ? 2 : 1;
  const int nt0 = wave * 2;
  short8 bfr[2][9];
  for (int t = 0; t < nts; t++) {
    const short* wp = W4T + ((size_t)blk * CP + (nt0 + t) * 16 + lm) * KA + q * 8;
#pragma unroll
    for (int kc = 0; kc < 9; kc++)
      bfr[t][kc] = *(const short8*)(wp + kc * 32);
  }
  // persistent MLP weight fragments (blocks 0..127)
  // w1f: as r6.  w2n: split-K slice — out-cols (wave*32 + t*16 + lm),
  // K rows n*64 + kc2*32 + q*8 .. +7 (16 VGPRs, same budget as before).
  short8 w1f[4], w2n[2][2], w3f;
  if (blk < 128) {
    const short* p1 = W1T + ((size_t)(n * 64 + nwt * 16 + lm)) * H + ks * 128 + q * 8;
#pragma unroll
    for (int kc = 0; kc < 4; kc++) w1f[kc] = *(const short8*)(p1 + kc * 32);
#pragma unroll
    for (int t = 0; t < 2; t++)
#pragma unroll
      for (int kc2 = 0; kc2 < 2; kc2++)
        w2n[t][kc2] = *(const short8*)(W2T +
            ((size_t)(wave * 32 + t * 16 + lm)) * WMH + n * 64 + kc2 * 32 + q * 8);
    w3f = *(const short8*)(W3T + ((size_t)(n * 16 + lm)) * H + wv3 * 32 + q * 8);
  }
  // LDS-resident LN params and bias slices
  for (int i = tid; i < WMH; i += 512) { g1s[i] = g1[i]; be1s[i] = be1[i]; }
  for (int i = tid; i < H; i += 512)   { g2s[i] = g2[i]; be2s[i] = be2[i]; }
  if (tid < 64) fb1s[tid] = fb1[n * 64 + tid];
  if (tid < H) fb2F[tid] = fb2[tid];
  if (tid < 16) fb3s[tid] = fb3[n * 16 + tid];
  if (tid < 128) zcol[tid] = z[(size_t)tid * H + blk];
  __syncthreads();

#pragma unroll 1
  for (int p = 0; p < NPH; p++) {
    const int seg = p >> 1, pm = p & 1;
    const float* dX = (pm ? dmid : dknot) + (size_t)seg * B * CP;
    const float scale = pm ? HSTEP : 0.5f * HSTEP;
    float* T2cur = T2d + (size_t)(p & 1) * (B * H);

    if (blk < 128) {
      // ---- S12a: t1 slice = X @ W1 + fb1 (LDS only), post LN1 partial stats
      if (p) poll256(eS4, p);
      {
        const uint* xsrc = Xu + (size_t)(m * 16) * H;
        int j0 = tid * 4, j1 = (tid + 512) * 4;
        uint4v v0, v1;
        CLOADB2(v0, v1, xsrc + j0, xsrc + j1);
        *(uint4v*)&xs[(j0 >> 8) * 260 + (j0 & 255)] = v0;
        *(uint4v*)&xs[(j1 >> 8) * 260 + (j1 & 255)] = v1;
      }
      __syncthreads();
      {
        f32x4 acc = {0.f, 0.f, 0.f, 0.f};
        const int xb = lm * 260 + ks * 128 + q * 8;
#pragma unroll
        for (int kc = 0; kc < 4; kc++) {
          uint4v a = *(const uint4v*)&xs[xb + kc * 32];
          uint4v b = *(const uint4v*)&xs[xb + kc * 32 + 4];
          short8 ah, al;
          unpk(a, b, ah, al);
          acc = MFMA16(ah, w1f[kc], acc);
          acc = MFMA16(al, w1f[kc], acc);
        }
#pragma unroll
        for (int r = 0; r < 4; r++) red2[wave][(q * 4 + r) * 16 + lm] = acc[r];
      }
      __syncthreads();
      if (wave < 4) {
#pragma unroll
        for (int r = 0; r < 4; r++) {
          int idx = (q * 4 + r) * 16 + lm;
          t1s[q * 4 + r][wave * 16 + lm] =
              red2[wave][idx] + red2[wave + 4][idx] + fb1s[wave * 16 + lm];
        }
      }
      __syncthreads();
      if (tid < 256) {
        int row = tid >> 4, cg = tid & 15;
        float s = 0.f, ss = 0.f;
#pragma unroll
        for (int j = 0; j < 4; j++) {
          float v = t1s[row][cg * 4 + j];
          s += v; ss += v * v;
        }
        s += __shfl_xor(s, 1); ss += __shfl_xor(ss, 1);
        s += __shfl_xor(s, 2); ss += __shfl_xor(ss, 2);
        s += __shfl_xor(s, 4); ss += __shfl_xor(ss, 4);
        s += __shfl_xor(s, 8); ss += __shfl_xor(ss, 8);
        if (cg == 0) {
          cstoref(statsG + (size_t)(m * 16 + n) * 32 + row * 2, s);
          cstoref(statsG + (size_t)(m * 16 + n) * 32 + row * 2 + 1, ss);
        }
      }
      post(eS1 + m * 16 + n, p + 1);

      // ---- S12b: stats hop, then partial-K T2 += relu(LN1(t1s)) @ W2slice
      poll16(eS1 + m * 16, p + 1);
      ((float*)red2)[tid] = cloadf(statsG + (size_t)m * 512 + tid);
      __syncthreads();
      if (tid < 32) {
        float s = 0.f;
#pragma unroll
        for (int nn = 0; nn < 16; nn++) s += ((float*)red2)[nn * 32 + tid];
        fstat[tid] = s;
      }
      __syncthreads();
      {
        float mean = fstat[lm * 2] * (1.f / WMH);
        float var  = fstat[lm * 2 + 1] * (1.f / WMH) - mean * mean;
        float rsv  = rsqrtf(var + EPS);
        f32x4 acc0 = {0.f, 0.f, 0.f, 0.f}, acc1 = {0.f, 0.f, 0.f, 0.f};
#pragma unroll
        for (int kc2 = 0; kc2 < 2; kc2++) {
          const float* tp = &t1s[lm][kc2 * 32 + q * 8];
          short8 ah, al;
#pragma unroll
          for (int jj = 0; jj < 8; jj++) {
            int gcol = n * 64 + kc2 * 32 + q * 8 + jj;
            float a = fmaxf((tp[jj] - mean) * rsv * g1s[gcol] + be1s[gcol], 0.f);
            short hi = f2bf(a);
            ah[jj] = hi;
            al[jj] = f2bf(a - bf2f(hi));
          }
          acc0 = MFMA16(ah, w2n[0][kc2], acc0);
          acc0 = MFMA16(al, w2n[0][kc2], acc0);
          acc1 = MFMA16(ah, w2n[1][kc2], acc1);
          acc1 = MFMA16(al, w2n[1][kc2], acc1);
        }
#pragma unroll
        for (int r = 0; r < 4; r++) {
          int row = m * 16 + q * 4 + r;
          int c0 = wave * 32 + lm;
          float v0 = acc0[r], v1 = acc1[r];
          if (n == 0) { v0 += fb2F[c0]; v1 += fb2F[c0 + 16]; }
          catomadd(T2cur + (size_t)row * H + c0, v0);
          catomadd(T2cur + (size_t)row * H + c0 + 16, v1);
        }
      }
      post(eS2 + m * 16 + n, p + 1);

      // ---- S3: t3 slice -> frag-major packed bf16, group-local wait ----
      poll16(eS2 + m * 16, p + 1);
      const float* t2p = T2cur + (size_t)(m * 16 + lm) * H + wv3 * 32 + q * 8;
      uint4v u0, u1;
      CLOAD2(u0, u1, t2p);
      {
        float s = 0.f, ss = 0.f;
#pragma unroll
        for (int e = 0; e < 4; e++) {
          float v0 = __uint_as_float(u0[e]), v1 = __uint_as_float(u1[e]);
          s += v0 + v1; ss += v0 * v0 + v1 * v1;
        }
        s += __shfl_xor(s, 16); ss += __shfl_xor(ss, 16);
        s += __shfl_xor(s, 32); ss += __shfl_xor(ss, 32);
        if (q == 0) { red2[wave][lm] = s; red2[wave][16 + lm] = ss; }
        __syncthreads();
        float S = 0.f, SS = 0.f;
#pragma unroll
        for (int w = 0; w < 8; w++) { S += red2[w][lm]; SS += red2[w][16 + lm]; }
        float mean = S * (1.f / H);
        float var  = SS * (1.f / H) - mean * mean;
        float rsv  = rsqrtf(var + EPS);
        __syncthreads();
        int kg = wv3 * 32 + q * 8;
        short8 ah, al;
#pragma unroll
        for (int jj = 0; jj < 8; jj++) {
          float v = __uint_as_float((jj < 4 ? u0[jj & 3] : u1[jj & 3]));
          float a = fmaxf((v - mean) * rsv * g2s[kg + jj] + be2s[kg + jj], 0.f);
          short hi = f2bf(a);
          ah[jj] = hi;
          al[jj] = f2bf(a - bf2f(hi));
        }
        f32x4 acc = {0.f, 0.f, 0.f, 0.f};
        acc = MFMA16(ah, w3f, acc);
        acc = MFMA16(al, w3f, acc);
#pragma unroll
        for (int r = 0; r < 4; r++) red2[wave][(q * 4 + r) * 16 + lm] = acc[r];
      }
      __syncthreads();
      if (tid < 256) {
        int ri = tid >> 4, ci = tid & 15;
        float v = fb3s[ci];
#pragma unroll
        for (int w = 0; w < 8; w++) v += red2[w][tid];
        v = fmaxf(v, 0.f);
        float vo = __shfl_xor(v, 1);
        if ((ci & 1) == 0) {
          int kglob = n * 16 + ci;
          int d = (m * 9 + (kglob >> 5)) * 64 + ((kglob >> 3) & 3) * 16 + ri;
          uint u = ((uint)(unsigned short)f2bf(vo) << 16)
                 | (unsigned short)f2bf(v);
          cstoreu(t3u + d * 4 + ((kglob & 7) >> 1), u);
        }
      }
      post(eS3 + m * 16 + n, p + 1);
    } else {
      // idle S4-only block: prefetch next phase's dX slice into this XCD's L2
      if (p + 1 < NPH) {
        const int seg2 = (p + 1) >> 1, pm2 = (p + 1) & 1;
        const float* dX2 = (pm2 ? dmid : dknot) + (size_t)seg2 * B * CP;
        int i0 = tid * 64;
        if (i0 > B * CP - 64) i0 = B * CP - 64;
        int i1 = i0 + 32;
        float t0, t1;
        asm volatile("global_load_dword %0, %2, off\n\t"
                     "global_load_dword %1, %3, off\n\t"
                     "s_waitcnt vmcnt(0)"
                     : "=&v"(t0), "=&v"(t1)
                     : "v"(dX2 + i0), "v"(dX2 + i1) : "memory");
        asm volatile("" :: "v"(t0), "v"(t1));
      }
    }

    // ---- S4: all 256 blocks, h = blk ----
    {
      poll128(eS3, p + 1);
      // MLP blocks: zero the consumed T2 parity buffer for reuse at p+2
      // (safe: poll128(eS3) proves every S3 read of T2cur is complete).
      if (blk < 128 && tid < 256) {
        int ri = tid >> 4, ci = tid & 15;
        cstoref(T2cur + (size_t)(m * 16 + ri) * H + n * 16 + ci, 0.f);
      }
      {
        // stripe-rotated t3 broadcast load (de-synchronized across blocks)
        int s0 = blk % 9;
        int s1 = s0 + 1 >= 9 ? s0 + 1 - 9 : s0 + 1;
        int s2 = s1 + 1 >= 9 ? s1 + 1 - 9 : s1 + 1;
        int s3 = s2 + 1 >= 9 ? s2 + 1 - 9 : s2 + 1;
        int s4 = s3 + 1 >= 9 ? s3 + 1 - 9 : s3 + 1;
        int s5 = s4 + 1 >= 9 ? s4 + 1 - 9 : s4 + 1;
        int s6 = s5 + 1 >= 9 ? s5 + 1 - 9 : s5 + 1;
        int s7 = s6 + 1 >= 9 ? s6 + 1 - 9 : s6 + 1;
        int s8 = s7 + 1 >= 9 ? s7 + 1 - 9 : s7 + 1;
        const uint* tb = t3u + tid * 4;
        uint4v r0, r1, r2, r3, r4, r5, r6, r7, r8;
        CLOAD9(r0, r1, r2, r3, r4, r5, r6, r7, r8,
               tb + s0 * 2048, tb + s1 * 2048, tb + s2 * 2048,
               tb + s3 * 2048, tb + s4 * 2048, tb + s5 * 2048,
               tb + s6 * 2048, tb + s7 * 2048, tb + s8 * 2048);
        *(uint4v*)(t3s + (size_t)s0 * 4096 + tid * 8) = r0;
        *(uint4v*)(t3s + (size_t)s1 * 4096 + tid * 8) = r1;
        *(uint4v*)(t3s + (size_t)s2 * 4096 + tid * 8) = r2;
        *(uint4v*)(t3s + (size_t)s3 * 4096 + tid * 8) = r3;
        *(uint4v*)(t3s + (size_t)s4 * 4096 + tid * 8) = r4;
        *(uint4v*)(t3s + (size_t)s5 * 4096 + tid * 8) = r5;
        *(uint4v*)(t3s + (size_t)s6 * 4096 + tid * 8) = r6;
        *(uint4v*)(t3s + (size_t)s7 * 4096 + tid * 8) = r7;
        *(uint4v*)(t3s + (size_t)s8 * 4096 + tid * 8) = r8;
      }
      __syncthreads();
      for (int mm = 0; mm < 8; mm++) {
        short8 afr[9];
#pragma unroll
        for (int kc = 0; kc < 9; kc++)
          afr[kc] = *(const short8*)(t3s + (size_t)((mm * 9 + kc) * 64 + lane) * 8);
        f32x4 acc0 = {0.f, 0.f, 0.f, 0.f}, acc1 = {0.f, 0.f, 0.f, 0.f};
#pragma unroll
        for (int kc = 0; kc < 9; kc++) {
          acc0 = MFMA16(afr[kc], bfr[0][kc], acc0);
          if (nts > 1) acc1 = MFMA16(afr[kc], bfr[1][kc], acc1);
        }
        float part[4];
#pragma unroll
        for (int r = 0; r < 4; r++) {
          int row = mm * 16 + q * 4 + r;
          float pv = acc0[r] * dX[(size_t)row * CP + nt0 * 16 + lm];
          if (nts > 1) pv += acc1[r] * dX[(size_t)row * CP + (nt0 + 1) * 16 + lm];
          part[r] = pv;
        }
#pragma unroll
        for (int r = 0; r < 4; r++) {
          part[r] += __shfl_xor(part[r], 1);
          part[r] += __shfl_xor(part[r], 2);
          part[r] += __shfl_xor(part[r], 4);
          part[r] += __shfl_xor(part[r], 8);
        }
        if (lm == 0) {
#pragma unroll
          for (int r = 0; r < 4; r++) red4[wave][mm * 16 + q * 4 + r] = part[r];
        }
      }
      __syncthreads();
      if (tid < 128) {
        int row = tid;
        float s = 0.f;
#pragma unroll
        for (int w = 0; w < 8; w++) s += red4[w][row];
        float zo = zcol[row] + scale * s;
        if (pm) zcol[row] = zo;
        if (p == NPH - 1) z[(size_t)row * H + blk] = zo;
        short hi = f2bf(zo);
        short lo = f2bf(zo - bf2f(hi));
        cstoreu(Xu + (size_t)row * H + blk,
                ((uint)(unsigned short)hi << 16) | (unsigned short)lo);
      }
      post(eS4 + blk, p + 1);
    }
  }
}

// ---------------------------------------------------------------------------
// Kernel 6: output heads
// ---------------------------------------------------------------------------
__global__ __launch_bounds__(256) void k_final(const float* __restrict__ z,
    const float* __restrict__ yW1, const float* __restrict__ yb1,
    const float* __restrict__ yW2, const float* __restrict__ yb2,
    const float* __restrict__ zW1, const float* __restrict__ zb1,
    const float* __restrict__ zW2, const float* __restrict__ zb2,
    float* __restrict__ out) {
  __shared__ float ht[H];
  __shared__ float ry[128];
  __shared__ float rz[H];
  int b = blockIdx.x, tid = threadIdx.x;
  ht[tid] = z[(size_t)b * H + tid];
  __syncthreads();
  if (tid < 128) {
    float s = yb1[tid];
    for (int k = 0; k < H; k++) s += ht[k] * yW1[k * 128 + tid];
    ry[tid] = fmaxf(s, 0.f);
  }
  {
    float s = zb1[tid];
    for (int k = 0; k < H; k++) s += ht[k] * zW1[k * H + tid];
    rz[tid] = fmaxf(s, 0.f);
  }
  __syncthreads();
  if (tid < 64) {
    float sv = ry[tid] * yW2[tid] + ry[tid + 64] * yW2[tid + 64];
    for (int off = 32; off > 0; off >>= 1) sv += __shfl_down(sv, off);
    if (tid == 0) out[b] = sv + yb2[0];
  }
  if (tid < D) {
    float s = zb2[tid];
    for (int k = 0; k < H; k++) s += rz[k] * zW2[k * D + tid];
    out[B + b * D + tid] = s;
  }
  out[B + B * D + (size_t)b * H + tid] = ht[tid];
}

// ---------------------------------------------------------------------------
extern "C" void kernel_launch(void* const* d_in, const int* in_sizes, int n_in,
                              void* d_out, int out_size, void* d_ws, size_t ws_size,
                              hipStream_t stream) {
  const float* x   = (const float*)d_in[0];
  const float* hW1 = (const float*)d_in[1];
  const float* hb1 = (const float*)d_in[2];
  const float* hW2 = (const float*)d_in[3];
  const float* hb2 = (const float*)d_in[4];
  const float* fW1 = (const float*)d_in[5];
  const float* fb1 = (const float*)d_in[6];
  const float* g1  = (const float*)d_in[7];
  const float* be1 = (const float*)d_in[8];
  const float* fW2 = (const float*)d_in[9];
  const float* fb2 = (const float*)d_in[10];
  const float* g2  = (const float*)d_in[11];
  const float* be2 = (const float*)d_in[12];
  const float* fW3 = (const float*)d_in[13];
  const float* fb3 = (const float*)d_in[14];
  const float* fW4 = (const float*)d_in[15];
  const float* fb4 = (const float*)d_in[16];
  const float* yW1 = (const float*)d_in[17];
  const float* yb1 = (const float*)d_in[18];
  const float* yW2 = (const float*)d_in[19];
  const float* yb2 = (const float*)d_in[20];
  const float* zW1 = (const float*)d_in[21];
  const float* zb1 = (const float*)d_in[22];
  const float* zW2 = (const float*)d_in[23];
  const float* zb2 = (const float*)d_in[24];
  const float* sg  = (const float*)d_in[25];
  const float* sb  = (const float*)d_in[26];

  float* ws     = (float*)d_ws;
  float* dknot  = ws;                               // 1,935,360 f
  float* dmid   = dknot + (size_t)NSEG * B * CP;    // 1,935,360 f
  float* z      = dmid + (size_t)NSEG * B * CP;     // 32,768 f
  float* T2d    = z + B * H;                        // 2 x 32,768 f (parity)
  float* statsG = T2d + (size_t)2 * B * H;          // 4,096 f
  uint* Xu      = (uint*)(statsG + 4096);           // 32,768 u
  uint* t3u     = Xu + B * H;                       // 18,432 u
  int* flags    = (int*)(t3u + B * KA / 2);         // 1024 i (epoch flags)
  short* w1T    = (short*)(flags + 1024);           // 262,144 s
  short* w2T    = w1T + H * WMH;                    // 262,144 s
  short* w3T    = w2T + H * WMH;                    // 65,536 s
  short* W4T    = w3T + H * H;                      // 17,694,720 s
  float* y      = (float*)W4T;                      // temp alias (dead before W4T built)

  hipLaunchKernelGGL(k_logsig, dim3(B), dim3(256), 0, stream, x, sg, sb, y);
  hipLaunchKernelGGL(k_spline, dim3(B), dim3(256), 0, stream, y, dknot, dmid);
  hipLaunchKernelGGL(k_h0,     dim3(B), dim3(256), 0, stream, x, hW1, hb1, hW2, hb2, z, Xu);
  hipLaunchKernelGGL(k_prep_t,   dim3(928, 4), dim3(256), 0, stream, fW4, W4T);
  hipLaunchKernelGGL(k_prep_pad, dim3(9728),   dim3(256), 0, stream, fb4, W4T);
  hipLaunchKernelGGL(k_prep_wt,  dim3(16, 4),  dim3(256), 0, stream, fW1, w1T, H, WMH);
  hipLaunchKernelGGL(k_prep_wt,  dim3(4, 16),  dim3(256), 0, stream, fW2, w2T, WMH, H);
  hipLaunchKernelGGL(k_prep_wt,  dim3(4, 4),   dim3(256), 0, stream, fW3, w3T, H, H);
  hipLaunchKernelGGL(k_prep_t3pad, dim3(1), dim3(128), 0, stream, (short*)t3u);
  hipLaunchKernelGGL(k_prep_zero, dim3(4), dim3(256), 0, stream, flags, 1024);
  hipLaunchKernelGGL(k_prep_zero, dim3(256), dim3(256), 0, stream, (int*)T2d, 2 * B * H);

  void* args[] = {
    (void*)&w1T, (void*)&fb1, (void*)&g1, (void*)&be1,
    (void*)&w2T, (void*)&fb2, (void*)&g2, (void*)&be2,
    (void*)&w3T, (void*)&fb3, (void*)&W4T,
    (void*)&dknot, (void*)&dmid,
    (void*)&z, (void*)&Xu, (void*)&t3u,
    (void*)&T2d, (void*)&statsG, (void*)&flags
  };
  hipLaunchCooperativeKernel((const void*)k_scan, dim3(256), dim3(512), args, 0, stream);

  hipLaunchKernelGGL(k_final, dim3(B), dim3(256), 0, stream, z,
                     yW1, yb1, yW2, yb2, zW1, zb1, zW2, zb2, (float*)d_out);
}